// Round 2
// baseline (1648.858 us; speedup 1.0000x reference)
//
#include <hip/hip_runtime.h>
#include <math.h>

#define CC   128
#define HH   16
#define WW   16
#define BB   32
#define VV   8192
#define NELEM (BB*CC*HH*WW)   // 1,048,576

#define QT 64
#define VT 64

// ---------------- e_sq ----------------
__global__ void esq_kernel(const float* __restrict__ emb, float* __restrict__ esq) {
    int v = blockIdx.x * blockDim.x + threadIdx.x;
    const float* row = emb + (size_t)v * CC;
    float s = 0.f;
#pragma unroll
    for (int c = 0; c < CC; c += 4) {
        float4 e4 = *(const float4*)(row + c);
        s += e4.x*e4.x + e4.y*e4.y + e4.z*e4.z + e4.w*e4.w;
    }
    esq[v] = s;
}

// ---------------- pool: rest[n][c] = blockmean(f - f_hat) ----------------
__global__ void pool_kernel(const float* __restrict__ f, const float* __restrict__ fh,
                            float* __restrict__ rest, int pn) {
    int t = blockIdx.x * blockDim.x + threadIdx.x;
    int Ntot = BB * pn * pn * CC;
    if (t >= Ntot) return;
    int c = t % CC;
    int n = t / CC;
    int px = n % pn;
    int py = (n / pn) % pn;
    int b  = n / (pn * pn);
    int s  = HH / pn;
    size_t o = (((size_t)b * CC + c) * HH + py * s) * WW + px * s;
    float acc = 0.f;
    for (int dy = 0; dy < s; dy++)
        for (int dx = 0; dx < s; dx++)
            acc += f[o + dy * WW + dx] - fh[o + dy * WW + dx];
    rest[(size_t)n * CC + c] = acc * (1.f / (float)(s * s));
}

// ---------------- distance + partial argmin ----------------
// grid = (qblocks, vsplit), block = 256.
template <bool FULL>
__global__ __launch_bounds__(256)
void dist_kernel(const float* __restrict__ rest,
                 const float* __restrict__ f, const float* __restrict__ fh,
                 const float* __restrict__ emb, const float* __restrict__ esq,
                 float* __restrict__ pbD, int* __restrict__ pbI,
                 int N, int vsplit) {
    __shared__ __align__(16) float Rt[CC * QT];  // [c][q] 32 KB
    __shared__ __align__(16) float Et[CC * VT];  // [c][v] 32 KB
    int tid = threadIdx.x;
    int qb  = blockIdx.x;
    int vs  = blockIdx.y;
    int q_base = qb * QT;

    if (FULL) {
        // queries are full-res positions n=(b,y,x); residual = f - f_hat on the fly
        for (int id = tid; id < QT * CC; id += 256) {
            int q = id & 63, c = id >> 6;
            int n = q_base + q;              // N == 8192, always valid
            int b = n >> 8, rem = n & 255;
            size_t a = (size_t)b * (CC * 256) + c * 256 + rem;
            Rt[c * QT + q] = f[a] - fh[a];
        }
    } else {
        for (int id = tid; id < QT * (CC / 4); id += 256) {
            int q  = id / (CC / 4);
            int c4 = id % (CC / 4);
            float4 val = make_float4(0.f, 0.f, 0.f, 0.f);
            if (q_base + q < N) val = *(const float4*)(rest + (size_t)(q_base + q) * CC + c4 * 4);
            int c = c4 * 4;
            Rt[(c + 0) * QT + q] = val.x;
            Rt[(c + 1) * QT + q] = val.y;
            Rt[(c + 2) * QT + q] = val.z;
            Rt[(c + 3) * QT + q] = val.w;
        }
    }

    int qg = tid & 15, vg = tid >> 4;
    int q0 = qg * 4, v0 = vg * 4;
    float bestD[4] = {INFINITY, INFINITY, INFINITY, INFINITY};
    int   bestI[4] = {0, 0, 0, 0};

    int chunksPer = (VV / VT) / vsplit;
    int ch_begin  = vs * chunksPer;

    for (int ch = 0; ch < chunksPer; ch++) {
        int v_glob0 = (ch_begin + ch) * VT;
        __syncthreads();
        for (int id = tid; id < VT * (CC / 4); id += 256) {
            int v  = id / (CC / 4);
            int c4 = id % (CC / 4);
            float4 val = *(const float4*)(emb + (size_t)(v_glob0 + v) * CC + c4 * 4);
            int c = c4 * 4;
            Et[(c + 0) * VT + v] = val.x;
            Et[(c + 1) * VT + v] = val.y;
            Et[(c + 2) * VT + v] = val.z;
            Et[(c + 3) * VT + v] = val.w;
        }
        __syncthreads();

        float acc[4][4] = {};
#pragma unroll 4
        for (int c = 0; c < CC; c++) {
            const float4 rq = *(const float4*)(Rt + c * QT + q0);
            const float4 ev = *(const float4*)(Et + c * VT + v0);
            float r[4] = {rq.x, rq.y, rq.z, rq.w};
            float e[4] = {ev.x, ev.y, ev.z, ev.w};
#pragma unroll
            for (int qi = 0; qi < 4; qi++)
#pragma unroll
                for (int vi = 0; vi < 4; vi++)
                    acc[qi][vi] = fmaf(r[qi], e[vi], acc[qi][vi]);
        }
#pragma unroll
        for (int vi = 0; vi < 4; vi++) {
            int v = v_glob0 + v0 + vi;
            float eq = esq[v];
#pragma unroll
            for (int qi = 0; qi < 4; qi++) {
                float d = eq - 2.f * acc[qi][vi];
                if (d < bestD[qi]) { bestD[qi] = d; bestI[qi] = v; }  // ascending v => first-min
            }
        }
    }

    __syncthreads();
    float* redD = Rt;          // [QT][16]
    int*   redI = (int*)Et;    // [QT][16]
#pragma unroll
    for (int qi = 0; qi < 4; qi++) {
        redD[(q0 + qi) * 16 + vg] = bestD[qi];
        redI[(q0 + qi) * 16 + vg] = bestI[qi];
    }
    __syncthreads();
    if (tid < QT) {
        int q = tid;
        float bd = redD[q * 16];
        int   bi = redI[q * 16];
        for (int j = 1; j < 16; j++) {
            float d  = redD[q * 16 + j];
            int   i2 = redI[q * 16 + j];
            if (d < bd || (d == bd && i2 < bi)) { bd = d; bi = i2; }
        }
        if (q_base + q < N) {
            pbD[(size_t)(q_base + q) * vsplit + vs] = bd;
            pbI[(size_t)(q_base + q) * vsplit + vs] = bi;
        }
    }
}

// ---------------- final argmin across vsplit ----------------
__global__ void argmin_reduce(const float* __restrict__ pbD, const int* __restrict__ pbI,
                              int* __restrict__ idx, int N, int vsplit) {
    int q = blockIdx.x * blockDim.x + threadIdx.x;
    if (q >= N) return;
    float bd = pbD[(size_t)q * vsplit];
    int   bi = pbI[(size_t)q * vsplit];
    for (int j = 1; j < vsplit; j++) {
        float d  = pbD[(size_t)q * vsplit + j];
        int   i2 = pbI[(size_t)q * vsplit + j];
        if (d < bd || (d == bd && i2 < bi)) { bd = d; bi = i2; }
    }
    idx[q] = bi;
}

// ---------------- Keys cubic a=-0.5 (matches jax) ----------------
__device__ __forceinline__ float cubic_k(float x) {
    if (x <= 1.f) return (1.5f * x - 2.5f) * x * x + 1.f;
    if (x < 2.f)  return ((-0.5f * x + 2.5f) * x - 4.f) * x + 2.f;
    return 0.f;
}

// ---------------- fused upsample + conv3x3 + phi + f_hat update + loss ----------------
// grid = (cog=16, bpair=16), block = 256 (16x16). PN==16 -> direct gather (no interp).
template <int PN>
__global__ __launch_bounds__(256)
void conv_fused(const float* __restrict__ emb, const int* __restrict__ idx,
                const float* __restrict__ pw, const float* __restrict__ pb,
                const float* __restrict__ f, float* __restrict__ f_hat,
                float* __restrict__ lacc, int kphi) {
    __shared__ __align__(16) float in2[2 * 18 * 18];  // zero halo
    __shared__ __align__(16) float wl[9 * 8];         // [kk][co]
    __shared__ float S[2 * PN * PN];
    __shared__ int   idxL[2 * PN * PN];
    __shared__ float lred[4];

    const int t = threadIdx.x;
    const int x = t & 15, y = t >> 4;
    const int cog = blockIdx.x;
    const int b0  = blockIdx.y * 2;

    for (int i = t; i < 2 * 18 * 18; i += 256) in2[i] = 0.f;
    for (int i = t; i < 2 * PN * PN; i += 256) idxL[i] = idx[b0 * PN * PN + i];

    // per-thread bicubic taps (thread-invariant across cin)
    float wy[4], wx[4];
    int iy0 = 0, ix0 = 0;
    if (PN < 16) {
        const float sc = (float)PN / 16.f;
        float sy = (y + 0.5f) * sc - 0.5f;
        float sx = (x + 0.5f) * sc - 0.5f;
        iy0 = (int)floorf(sy) - 1;
        ix0 = (int)floorf(sx) - 1;
        float ssy = 0.f, ssx = 0.f;
#pragma unroll
        for (int k = 0; k < 4; k++) {
            int iy = iy0 + k, ix = ix0 + k;
            float a = (iy >= 0 && iy < PN) ? cubic_k(fabsf(sy - (float)iy)) : 0.f;
            float b = (ix >= 0 && ix < PN) ? cubic_k(fabsf(sx - (float)ix)) : 0.f;
            wy[k] = a; ssy += a;
            wx[k] = b; ssx += b;
        }
        float ry = 1.f / ssy, rx = 1.f / ssx;
#pragma unroll
        for (int k = 0; k < 4; k++) { wy[k] *= ry; wx[k] *= rx; }
    }

    const float* wbase = pw + ((size_t)kphi * CC + cog * 8) * (CC * 9);
    float acc[2][8] = {};
    float hvv[2][8];
    __syncthreads();  // idxL / halo ready

    for (int cin = 0; cin < CC; cin++) {
        // (top of iter: previous conv reads of S/wl/in2 complete via sync at end of loop body)
        if (PN < 16) {
            for (int i = t; i < 2 * PN * PN; i += 256)
                S[i] = emb[(size_t)idxL[i] * CC + cin];
        }
        if (t < 72) {
            int co = t / 9, kk = t % 9;
            wl[kk * 8 + co] = wbase[(size_t)(co * CC + cin) * 9 + kk];
        }
        __syncthreads();  // S, wl ready

        float hv0, hv1;
        if (PN == 16) {
            hv0 = emb[(size_t)idxL[y * 16 + x] * CC + cin];
            hv1 = emb[(size_t)idxL[256 + y * 16 + x] * CC + cin];
        } else {
            hv0 = 0.f; hv1 = 0.f;
#pragma unroll
            for (int k4 = 0; k4 < 4; k4++) {
                int iy = iy0 + k4;
                if (iy < 0 || iy >= PN) continue;
                float r0 = 0.f, r1 = 0.f;
#pragma unroll
                for (int j4 = 0; j4 < 4; j4++) {
                    int ix = ix0 + j4;
                    if (ix < 0 || ix >= PN) continue;
                    r0 = fmaf(wx[j4], S[iy * PN + ix], r0);
                    r1 = fmaf(wx[j4], S[PN * PN + iy * PN + ix], r1);
                }
                hv0 = fmaf(wy[k4], r0, hv0);
                hv1 = fmaf(wy[k4], r1, hv1);
            }
        }
        in2[(y + 1) * 18 + (x + 1)] = hv0;
        in2[324 + (y + 1) * 18 + (x + 1)] = hv1;
        if ((cin >> 3) == cog) { int co = cin & 7; hvv[0][co] = hv0; hvv[1][co] = hv1; }
        __syncthreads();  // in2 ready

#pragma unroll
        for (int ky = 0; ky < 3; ky++) {
#pragma unroll
            for (int kx = 0; kx < 3; kx++) {
                float v0 = in2[(y + ky) * 18 + (x + kx)];
                float v1 = in2[324 + (y + ky) * 18 + (x + kx)];
#pragma unroll
                for (int co = 0; co < 8; co++) {
                    float w = wl[(ky * 3 + kx) * 8 + co];
                    acc[0][co] = fmaf(v0, w, acc[0][co]);
                    acc[1][co] = fmaf(v1, w, acc[1][co]);
                }
            }
        }
        __syncthreads();  // conv reads done before next-iter staging
    }

    float lsum = 0.f;
#pragma unroll
    for (int p = 0; p < 2; p++) {
#pragma unroll
        for (int co = 0; co < 8; co++) {
            int cg = cog * 8 + co;
            size_t gi = (((size_t)(b0 + p) * CC + cg) * HH + y) * WW + x;
            float conv = acc[p][co] + pb[kphi * CC + cg];
            float phi  = 0.5f * hvv[p][co] + 0.5f * conv;   // RATIO = 0.5
            float fh   = f_hat[gi] + phi;
            f_hat[gi]  = fh;
            float diff = fh - f[gi];
            lsum = fmaf(diff, diff, lsum);
        }
    }
#pragma unroll
    for (int off = 32; off; off >>= 1) lsum += __shfl_down(lsum, off, 64);
    if ((t & 63) == 0) lred[t >> 6] = lsum;
    __syncthreads();
    if (t == 0) atomicAdd(lacc, lred[0] + lred[1] + lred[2] + lred[3]);
}

__global__ void finalize_kernel(const float* __restrict__ lacc, float* __restrict__ out_loss) {
    // loss = (1+BETA)/SN * sum_si mean_si = 0.25 * accum / NELEM
    *out_loss = lacc[0] * (0.25f / (float)NELEM);
}

extern "C" void kernel_launch(void* const* d_in, const int* in_sizes, int n_in,
                              void* d_out, int out_size, void* d_ws, size_t ws_size,
                              hipStream_t stream) {
    const float* f   = (const float*)d_in[0];
    const float* emb = (const float*)d_in[1];
    const float* pw  = (const float*)d_in[2];
    const float* pb  = (const float*)d_in[3];
    float* out = (float*)d_out;
    float* ws  = (float*)d_ws;

    // compact workspace: ~1.32 MB total
    float* rest = ws;                       // 262144 floats (max N*C for pn<=8)
    float* esq  = ws + 262144;              // 8192
    int*   idx  = (int*)(ws + 270336);      // 8192
    float* pbD  = ws + 278528;              // 32768
    int*   pbI  = (int*)(ws + 311296);      // 32768
    float* lacc = ws + 344064;              // 1

    hipMemsetAsync(d_out, 0, (size_t)NELEM * sizeof(float), stream);  // f_hat = 0
    hipMemsetAsync(lacc, 0, sizeof(float), stream);

    esq_kernel<<<VV / 256, 256, 0, stream>>>(emb, esq);

    // mirror np.linspace(1/12, 11/12, 4) exactly in float64 (incl. endpoint overwrite)
    double start = 1.0 / 12.0;
    double stop  = 1.0 - 1.0 / 12.0;
    double step  = (stop - start) / 3.0;
    double ticks[4] = {start, 1.0 * step + start, 2.0 * step + start, stop};

    const int pns[5]     = {1, 2, 4, 8, 16};
    const int vsplit5[5] = {128, 128, 64, 16, 4};

    for (int si = 0; si < 5; si++) {
        int pn = pns[si];
        int N  = BB * pn * pn;
        double tt = (double)si / 4.0;
        int kphi = 0;
        double bd = fabs(ticks[0] - tt);
        for (int i = 1; i < 4; i++) {
            double d = fabs(ticks[i] - tt);
            if (d < bd) { bd = d; kphi = i; }   // np.argmin: first occurrence
        }

        int vsplit = vsplit5[si];
        int qb = (N + QT - 1) / QT;
        dim3 dgrid(qb, vsplit);

        if (pn < 16) {
            pool_kernel<<<(N * CC + 255) / 256, 256, 0, stream>>>(f, out, rest, pn);
            dist_kernel<false><<<dgrid, 256, 0, stream>>>(rest, f, out, emb, esq, pbD, pbI, N, vsplit);
        } else {
            dist_kernel<true><<<dgrid, 256, 0, stream>>>(rest, f, out, emb, esq, pbD, pbI, N, vsplit);
        }
        argmin_reduce<<<(N + 255) / 256, 256, 0, stream>>>(pbD, pbI, idx, N, vsplit);

        dim3 cgrid(16, 16);
        switch (pn) {
            case 1:  conv_fused<1><<<cgrid, 256, 0, stream>>>(emb, idx, pw, pb, f, out, lacc, kphi); break;
            case 2:  conv_fused<2><<<cgrid, 256, 0, stream>>>(emb, idx, pw, pb, f, out, lacc, kphi); break;
            case 4:  conv_fused<4><<<cgrid, 256, 0, stream>>>(emb, idx, pw, pb, f, out, lacc, kphi); break;
            case 8:  conv_fused<8><<<cgrid, 256, 0, stream>>>(emb, idx, pw, pb, f, out, lacc, kphi); break;
            default: conv_fused<16><<<cgrid, 256, 0, stream>>>(emb, idx, pw, pb, f, out, lacc, kphi); break;
        }
    }

    finalize_kernel<<<1, 1, 0, stream>>>(lacc, out + NELEM);
}

// Round 3
// 1278.103 us; speedup vs baseline: 1.2901x; 1.2901x over previous
//
#include <hip/hip_runtime.h>
#include <math.h>

#define CC   128
#define HH   16
#define WW   16
#define BB   32
#define VV   8192
#define NELEM (BB*CC*HH*WW)   // 1,048,576

typedef short short8 __attribute__((ext_vector_type(8)));
typedef float floatx4 __attribute__((ext_vector_type(4)));

#define LDST 72   // LDS row stride in bf16 elems: 64 + 8 pad (144 B, 16B-aligned, 2-way banks)

// ---------------- hi/lo bf16 split pack (RNE both) ----------------
__device__ __forceinline__ uint32_t pack_hilo(float x) {
    uint32_t u = __float_as_uint(x);
    uint32_t hb = (u + 0x7fffu + ((u >> 16) & 1u)) & 0xffff0000u;
    float hf = __uint_as_float(hb);
    float lo = x - hf;
    uint32_t ul = __float_as_uint(lo);
    uint32_t lb = ((ul + 0x7fffu + ((ul >> 16) & 1u)) >> 16) & 0xffffu;
    return hb | lb;
}

// ---------------- e_sq (exact fp32, same order as R2 which passed) ----------------
__global__ void esq_kernel(const float* __restrict__ emb, float* __restrict__ esq) {
    int v = blockIdx.x * blockDim.x + threadIdx.x;
    const float* row = emb + (size_t)v * CC;
    float s = 0.f;
#pragma unroll
    for (int c = 0; c < CC; c += 4) {
        float4 e4 = *(const float4*)(row + c);
        s += e4.x*e4.x + e4.y*e4.y + e4.z*e4.z + e4.w*e4.w;
    }
    esq[v] = s;
}

// ---------------- pack codebook to hi|lo u32 ----------------
__global__ void prepack_emb(const float* __restrict__ emb, uint32_t* __restrict__ ep) {
    int id = blockIdx.x * 256 + threadIdx.x;   // 262144 threads, 4 elems each
    int g = id % 32, v = id / 32;
    float4 e4 = *(const float4*)(emb + (size_t)v * CC + g * 4);
    uint4 o;
    o.x = pack_hilo(e4.x); o.y = pack_hilo(e4.y);
    o.z = pack_hilo(e4.z); o.w = pack_hilo(e4.w);
    *(uint4*)(ep + (size_t)v * CC + g * 4) = o;
}

// ---------------- pooled residual (f - f_hat), packed hi|lo ----------------
__global__ void pool_pack(const float* __restrict__ f, const float* __restrict__ fh,
                          uint32_t* __restrict__ rp, int pn) {
    int id = blockIdx.x * 256 + threadIdx.x;   // N*CC threads
    int c = id % CC;
    int n = id / CC;
    int px = n % pn;
    int py = (n / pn) % pn;
    int b  = n / (pn * pn);
    int s  = HH / pn;
    size_t o = (((size_t)b * CC + c) * HH + py * s) * WW + px * s;
    float acc = 0.f;
    for (int dy = 0; dy < s; dy++)
        for (int dx = 0; dx < s; dx++)
            acc += f[o + dy * WW + dx] - fh[o + dy * WW + dx];
    rp[id] = pack_hilo(acc * (1.f / (float)(s * s)));
}

// ---------------- MFMA distance + partial argmin ----------------
// grid = (ceil(N/128), vslices); block tile 128q x 128v; wave w: qh=w&1, vh=w>>1.
// Virtual K = 4 passes (hi*hi, lo*hi, hi*lo, lo*lo) over K=128 in 2 chunks of 64.
__global__ __launch_bounds__(256, 2)
void dist_mfma(const uint32_t* __restrict__ rp, const uint32_t* __restrict__ ep,
               const float* __restrict__ esq,
               float* __restrict__ pbD, int* __restrict__ pbI,
               int N, int vtPB) {
    __shared__ short Ah[128 * LDST];
    __shared__ short Al[128 * LDST];
    __shared__ short Bb[128 * LDST];

    const int tid  = threadIdx.x;
    const int wave = tid >> 6, lane = tid & 63;
    const int quad = lane >> 4, l15 = lane & 15;
    const int qh = wave & 1, vh = wave >> 1;
    const int qb0 = blockIdx.x * 128;
    const int vslices = gridDim.y;
    const int vbase = blockIdx.y * vtPB * 128;

    float bD[4][4];
    int   bI[4][4];
#pragma unroll
    for (int ti = 0; ti < 4; ti++)
#pragma unroll
        for (int r = 0; r < 4; r++) { bD[ti][r] = INFINITY; bI[ti][r] = 0; }

    const int sq = tid >> 1;                 // staging row
    const int jg = (tid & 1) * 32;           // staging col group

    for (int vt = 0; vt < vtPB; vt++) {
        int v0 = vbase + vt * 128;
        floatx4 acc[4][4];
        floatx4 z = {0.f, 0.f, 0.f, 0.f};
#pragma unroll
        for (int ti = 0; ti < 4; ti++)
#pragma unroll
            for (int tj = 0; tj < 4; tj++) acc[ti][tj] = z;

        for (int kp = 0; kp < 2; kp++) {
            __syncthreads();   // prior reads of Ah/Al/Bb complete
            {   // stage A (both halves). Rows >= N read stale-but-in-bounds data; outputs unwritten.
                const uint32_t* src = rp + (size_t)(qb0 + sq) * CC + kp * 64 + jg;
                uint32_t* wh = (uint32_t*)&Ah[sq * LDST + jg];
                uint32_t* wl = (uint32_t*)&Al[sq * LDST + jg];
#pragma unroll
                for (int j = 0; j < 32; j += 2) {
                    uint32_t p0 = src[j], p1 = src[j + 1];
                    wh[j >> 1] = (p0 >> 16) | (p1 & 0xffff0000u);
                    wl[j >> 1] = (p0 & 0xffffu) | (p1 << 16);
                }
            }
            for (int bsel = 0; bsel < 2; bsel++) {
                if (bsel) __syncthreads();   // prior mfma reads of Bb complete
                {   // stage B half (hi then lo)
                    const uint32_t* src = ep + (size_t)(v0 + sq) * CC + kp * 64 + jg;
                    uint32_t* wb = (uint32_t*)&Bb[sq * LDST + jg];
#pragma unroll
                    for (int j = 0; j < 32; j += 2) {
                        uint32_t p0 = src[j], p1 = src[j + 1];
                        uint32_t h0 = bsel ? (p0 & 0xffffu) : (p0 >> 16);
                        uint32_t h1 = bsel ? (p1 & 0xffffu) : (p1 >> 16);
                        wb[j >> 1] = h0 | (h1 << 16);
                    }
                }
                __syncthreads();
#pragma unroll
                for (int ks = 0; ks < 2; ks++) {
                    const int ko = ks * 32 + quad * 8;
                    short8 av[4], aw[4], bv[4];
#pragma unroll
                    for (int ti = 0; ti < 4; ti++)
                        av[ti] = *(const short8*)&Ah[(qh * 64 + ti * 16 + l15) * LDST + ko];
#pragma unroll
                    for (int ti = 0; ti < 4; ti++)
                        aw[ti] = *(const short8*)&Al[(qh * 64 + ti * 16 + l15) * LDST + ko];
#pragma unroll
                    for (int tj = 0; tj < 4; tj++)
                        bv[tj] = *(const short8*)&Bb[(vh * 64 + tj * 16 + l15) * LDST + ko];
#pragma unroll
                    for (int ti = 0; ti < 4; ti++)
#pragma unroll
                        for (int tj = 0; tj < 4; tj++) {
                            acc[ti][tj] = __builtin_amdgcn_mfma_f32_16x16x32_bf16(
                                av[ti], bv[tj], acc[ti][tj], 0, 0, 0);
                            acc[ti][tj] = __builtin_amdgcn_mfma_f32_16x16x32_bf16(
                                aw[ti], bv[tj], acc[ti][tj], 0, 0, 0);
                        }
                }
            }
        }

        // epilogue: dist = esq - 2*dot; per-lane running argmin (v ascending -> strict <)
#pragma unroll
        for (int tj = 0; tj < 4; tj++) {
            int vg = v0 + vh * 64 + tj * 16 + l15;
            float ev = esq[vg];
#pragma unroll
            for (int ti = 0; ti < 4; ti++)
#pragma unroll
                for (int r = 0; r < 4; r++) {
                    float d = fmaf(-2.f, acc[ti][tj][r], ev);
                    if (d < bD[ti][r]) { bD[ti][r] = d; bI[ti][r] = vg; }
                }
        }
    }

    // cross-lane reduce within each 16-lane group (same q-set, different v), tie -> lower v
#pragma unroll
    for (int ti = 0; ti < 4; ti++)
#pragma unroll
        for (int r = 0; r < 4; r++) {
            float d = bD[ti][r];
            int   v = bI[ti][r];
#pragma unroll
            for (int m = 1; m <= 8; m <<= 1) {
                float od = __shfl_xor(d, m, 64);
                int   ov = __shfl_xor(v, m, 64);
                if (od < d || (od == d && ov < v)) { d = od; v = ov; }
            }
            if (l15 == 0) {
                int q = qb0 + qh * 64 + ti * 16 + quad * 4 + r;
                if (q < N) {
                    size_t o = (size_t)q * (vslices * 2) + blockIdx.y * 2 + vh;
                    pbD[o] = d;
                    pbI[o] = v;
                }
            }
        }
}

// ---------------- final argmin across partials ----------------
__global__ void argmin_reduce(const float* __restrict__ pbD, const int* __restrict__ pbI,
                              int* __restrict__ idx, int N, int vsplit) {
    int q = blockIdx.x * blockDim.x + threadIdx.x;
    if (q >= N) return;
    float bd = pbD[(size_t)q * vsplit];
    int   bi = pbI[(size_t)q * vsplit];
    for (int j = 1; j < vsplit; j++) {
        float d  = pbD[(size_t)q * vsplit + j];
        int   i2 = pbI[(size_t)q * vsplit + j];
        if (d < bd || (d == bd && i2 < bi)) { bd = d; bi = i2; }
    }
    idx[q] = bi;
}

// ---------------- Keys cubic a=-0.5 (matches jax) ----------------
__device__ __forceinline__ float cubic_k(float x) {
    if (x <= 1.f) return (1.5f * x - 2.5f) * x * x + 1.f;
    if (x < 2.f)  return ((-0.5f * x + 2.5f) * x - 4.f) * x + 2.f;
    return 0.f;
}

// ---------------- fused upsample + conv3x3 + phi + f_hat update + loss ----------------
template <int PN>
__global__ __launch_bounds__(256)
void conv_fused(const float* __restrict__ emb, const int* __restrict__ idx,
                const float* __restrict__ pw, const float* __restrict__ pb,
                const float* __restrict__ f, float* __restrict__ f_hat,
                float* __restrict__ lacc, int kphi) {
    __shared__ __align__(16) float in2[2 * 18 * 18];  // zero halo
    __shared__ __align__(16) float wl[9 * 8];         // [kk][co]
    __shared__ float S[2 * PN * PN];
    __shared__ int   idxL[2 * PN * PN];
    __shared__ float lred[4];

    const int t = threadIdx.x;
    const int x = t & 15, y = t >> 4;
    const int cog = blockIdx.x;
    const int b0  = blockIdx.y * 2;

    for (int i = t; i < 2 * 18 * 18; i += 256) in2[i] = 0.f;
    for (int i = t; i < 2 * PN * PN; i += 256) idxL[i] = idx[b0 * PN * PN + i];

    float wy[4], wx[4];
    int iy0 = 0, ix0 = 0;
    if (PN < 16) {
        const float sc = (float)PN / 16.f;
        float sy = (y + 0.5f) * sc - 0.5f;
        float sx = (x + 0.5f) * sc - 0.5f;
        iy0 = (int)floorf(sy) - 1;
        ix0 = (int)floorf(sx) - 1;
        float ssy = 0.f, ssx = 0.f;
#pragma unroll
        for (int k = 0; k < 4; k++) {
            int iy = iy0 + k, ix = ix0 + k;
            float a = (iy >= 0 && iy < PN) ? cubic_k(fabsf(sy - (float)iy)) : 0.f;
            float b = (ix >= 0 && ix < PN) ? cubic_k(fabsf(sx - (float)ix)) : 0.f;
            wy[k] = a; ssy += a;
            wx[k] = b; ssx += b;
        }
        float ry = 1.f / ssy, rx = 1.f / ssx;
#pragma unroll
        for (int k = 0; k < 4; k++) { wy[k] *= ry; wx[k] *= rx; }
    }

    const float* wbase = pw + ((size_t)kphi * CC + cog * 8) * (CC * 9);
    float acc[2][8] = {};
    float hvv[2][8];
    __syncthreads();

    for (int cin = 0; cin < CC; cin++) {
        if (PN < 16) {
            for (int i = t; i < 2 * PN * PN; i += 256)
                S[i] = emb[(size_t)idxL[i] * CC + cin];
        }
        if (t < 72) {
            int co = t / 9, kk = t % 9;
            wl[kk * 8 + co] = wbase[(size_t)(co * CC + cin) * 9 + kk];
        }
        __syncthreads();

        float hv0, hv1;
        if (PN == 16) {
            hv0 = emb[(size_t)idxL[y * 16 + x] * CC + cin];
            hv1 = emb[(size_t)idxL[256 + y * 16 + x] * CC + cin];
        } else {
            hv0 = 0.f; hv1 = 0.f;
#pragma unroll
            for (int k4 = 0; k4 < 4; k4++) {
                int iy = iy0 + k4;
                if (iy < 0 || iy >= PN) continue;
                float r0 = 0.f, r1 = 0.f;
#pragma unroll
                for (int j4 = 0; j4 < 4; j4++) {
                    int ix = ix0 + j4;
                    if (ix < 0 || ix >= PN) continue;
                    r0 = fmaf(wx[j4], S[iy * PN + ix], r0);
                    r1 = fmaf(wx[j4], S[PN * PN + iy * PN + ix], r1);
                }
                hv0 = fmaf(wy[k4], r0, hv0);
                hv1 = fmaf(wy[k4], r1, hv1);
            }
        }
        in2[(y + 1) * 18 + (x + 1)] = hv0;
        in2[324 + (y + 1) * 18 + (x + 1)] = hv1;
        if ((cin >> 3) == cog) { int co = cin & 7; hvv[0][co] = hv0; hvv[1][co] = hv1; }
        __syncthreads();

#pragma unroll
        for (int ky = 0; ky < 3; ky++) {
#pragma unroll
            for (int kx = 0; kx < 3; kx++) {
                float v0 = in2[(y + ky) * 18 + (x + kx)];
                float v1 = in2[324 + (y + ky) * 18 + (x + kx)];
#pragma unroll
                for (int co = 0; co < 8; co++) {
                    float w = wl[(ky * 3 + kx) * 8 + co];
                    acc[0][co] = fmaf(v0, w, acc[0][co]);
                    acc[1][co] = fmaf(v1, w, acc[1][co]);
                }
            }
        }
        __syncthreads();
    }

    float lsum = 0.f;
#pragma unroll
    for (int p = 0; p < 2; p++) {
#pragma unroll
        for (int co = 0; co < 8; co++) {
            int cg = cog * 8 + co;
            size_t gi = (((size_t)(b0 + p) * CC + cg) * HH + y) * WW + x;
            float conv = acc[p][co] + pb[kphi * CC + cg];
            float phi  = 0.5f * hvv[p][co] + 0.5f * conv;   // RATIO = 0.5
            float fh   = f_hat[gi] + phi;
            f_hat[gi]  = fh;
            float diff = fh - f[gi];
            lsum = fmaf(diff, diff, lsum);
        }
    }
#pragma unroll
    for (int off = 32; off; off >>= 1) lsum += __shfl_down(lsum, off, 64);
    if ((t & 63) == 0) lred[t >> 6] = lsum;
    __syncthreads();
    if (t == 0) atomicAdd(lacc, lred[0] + lred[1] + lred[2] + lred[3]);
}

__global__ void finalize_kernel(const float* __restrict__ lacc, float* __restrict__ out_loss) {
    *out_loss = lacc[0] * (0.25f / (float)NELEM);   // (1+BETA)/SN * sum of means
}

extern "C" void kernel_launch(void* const* d_in, const int* in_sizes, int n_in,
                              void* d_out, int out_size, void* d_ws, size_t ws_size,
                              hipStream_t stream) {
    const float* f   = (const float*)d_in[0];
    const float* emb = (const float*)d_in[1];
    const float* pw  = (const float*)d_in[2];
    const float* pb  = (const float*)d_in[3];
    float* out = (float*)d_out;

    uint32_t* w32   = (uint32_t*)d_ws;
    uint32_t* rpack = w32;                          // 1,048,576 u32 (4 MB)
    uint32_t* epack = w32 + 1048576;                // 1,048,576 u32 (4 MB)
    float*    esq   = (float*)(w32 + 2097152);      // 8192
    int*      idx   = (int*)  (w32 + 2105344);      // 8192
    float*    pbD   = (float*)(w32 + 2113536);      // 131072
    int*      pbI   = (int*)  (w32 + 2244608);      // 131072
    float*    lacc  = (float*)(w32 + 2375680);      // 1

    hipMemsetAsync(d_out, 0, (size_t)NELEM * sizeof(float), stream);  // f_hat = 0
    hipMemsetAsync(lacc, 0, sizeof(float), stream);

    esq_kernel<<<VV / 256, 256, 0, stream>>>(emb, esq);
    prepack_emb<<<(VV * 32) / 256, 256, 0, stream>>>(emb, epack);

    // mirror np.linspace(1/12, 11/12, 4) exactly in float64
    double start = 1.0 / 12.0;
    double stop  = 1.0 - 1.0 / 12.0;
    double step  = (stop - start) / 3.0;
    double ticks[4] = {start, 1.0 * step + start, 2.0 * step + start, stop};

    const int pns[5]   = {1, 2, 4, 8, 16};
    const int gridy5[5] = {64, 64, 32, 16, 8};      // vslices
    const int vtPB5[5]  = {1, 1, 2, 4, 8};          // vtiles per block (x128 v)

    for (int si = 0; si < 5; si++) {
        int pn = pns[si];
        int N  = BB * pn * pn;
        double tt = (double)si / 4.0;
        int kphi = 0;
        double bd = fabs(ticks[0] - tt);
        for (int i = 1; i < 4; i++) {
            double d = fabs(ticks[i] - tt);
            if (d < bd) { bd = d; kphi = i; }   // np.argmin: first occurrence
        }

        pool_pack<<<(N * CC) / 256, 256, 0, stream>>>(f, out, rpack, pn);

        int qb = (N + 127) / 128;
        dim3 dgrid(qb, gridy5[si]);
        dist_mfma<<<dgrid, 256, 0, stream>>>(rpack, epack, esq, pbD, pbI, N, vtPB5[si]);

        argmin_reduce<<<(N + 255) / 256, 256, 0, stream>>>(pbD, pbI, idx, N, gridy5[si] * 2);

        dim3 cgrid(16, 16);
        switch (pn) {
            case 1:  conv_fused<1><<<cgrid, 256, 0, stream>>>(emb, idx, pw, pb, f, out, lacc, kphi); break;
            case 2:  conv_fused<2><<<cgrid, 256, 0, stream>>>(emb, idx, pw, pb, f, out, lacc, kphi); break;
            case 4:  conv_fused<4><<<cgrid, 256, 0, stream>>>(emb, idx, pw, pb, f, out, lacc, kphi); break;
            case 8:  conv_fused<8><<<cgrid, 256, 0, stream>>>(emb, idx, pw, pb, f, out, lacc, kphi); break;
            default: conv_fused<16><<<cgrid, 256, 0, stream>>>(emb, idx, pw, pb, f, out, lacc, kphi); break;
        }
    }

    finalize_kernel<<<1, 1, 0, stream>>>(lacc, out + NELEM);
}

// Round 4
// 967.270 us; speedup vs baseline: 1.7047x; 1.3214x over previous
//
#include <hip/hip_runtime.h>
#include <math.h>

#define CC   128
#define HH   16
#define WW   16
#define BB   32
#define VV   8192
#define NELEM (BB*CC*HH*WW)   // 1,048,576

typedef short short8 __attribute__((ext_vector_type(8)));
typedef float floatx4 __attribute__((ext_vector_type(4)));

#define LDST 72   // dist LDS row stride in bf16 elems (64 + 8 pad)

// ---------------- hi/lo bf16 split pack (RNE both) ----------------
__device__ __forceinline__ uint32_t pack_hilo(float x) {
    uint32_t u = __float_as_uint(x);
    uint32_t hb = (u + 0x7fffu + ((u >> 16) & 1u)) & 0xffff0000u;
    float hf = __uint_as_float(hb);
    float lo = x - hf;
    uint32_t ul = __float_as_uint(lo);
    uint32_t lb = ((ul + 0x7fffu + ((ul >> 16) & 1u)) >> 16) & 0xffffu;
    return hb | lb;
}

// ---------------- e_sq ----------------
__global__ void esq_kernel(const float* __restrict__ emb, float* __restrict__ esq) {
    int v = blockIdx.x * blockDim.x + threadIdx.x;
    const float* row = emb + (size_t)v * CC;
    float s = 0.f;
#pragma unroll
    for (int c = 0; c < CC; c += 4) {
        float4 e4 = *(const float4*)(row + c);
        s += e4.x*e4.x + e4.y*e4.y + e4.z*e4.z + e4.w*e4.w;
    }
    esq[v] = s;
}

// ---------------- pack codebook to hi|lo u32 ----------------
__global__ void prepack_emb(const float* __restrict__ emb, uint32_t* __restrict__ ep) {
    int id = blockIdx.x * 256 + threadIdx.x;
    int g = id % 32, v = id / 32;
    float4 e4 = *(const float4*)(emb + (size_t)v * CC + g * 4);
    uint4 o;
    o.x = pack_hilo(e4.x); o.y = pack_hilo(e4.y);
    o.z = pack_hilo(e4.z); o.w = pack_hilo(e4.w);
    *(uint4*)(ep + (size_t)v * CC + g * 4) = o;
}

// ---------------- pre-transpose + split conv weights: Wt[kphi][kk][cout][cin] ----------------
__global__ void prepack_w(const float* __restrict__ pw, short* __restrict__ Whi,
                          short* __restrict__ Wlo) {
    int id = blockIdx.x * 256 + threadIdx.x;      // 65536 = 4*128*128
    int ci = id & 127, cout = (id >> 7) & 127, kp = id >> 14;
    const float* src = pw + ((size_t)(kp * CC + cout) * CC + ci) * 9;
#pragma unroll
    for (int kk = 0; kk < 9; kk++) {
        uint32_t u = pack_hilo(src[kk]);
        size_t o = ((size_t)(kp * 9 + kk) * CC + cout) * CC + ci;
        Whi[o] = (short)(u >> 16);
        Wlo[o] = (short)(u & 0xffffu);
    }
}

// ---------------- pooled residual (f - f_hat), packed hi|lo ----------------
__global__ void pool_pack(const float* __restrict__ f, const float* __restrict__ fh,
                          uint32_t* __restrict__ rp, int pn) {
    int id = blockIdx.x * 256 + threadIdx.x;
    int c = id % CC;
    int n = id / CC;
    int px = n % pn;
    int py = (n / pn) % pn;
    int b  = n / (pn * pn);
    int s  = HH / pn;
    size_t o = (((size_t)b * CC + c) * HH + py * s) * WW + px * s;
    float acc = 0.f;
    for (int dy = 0; dy < s; dy++)
        for (int dx = 0; dx < s; dx++)
            acc += f[o + dy * WW + dx] - fh[o + dy * WW + dx];
    rp[id] = pack_hilo(acc * (1.f / (float)(s * s)));
}

// ---------------- MFMA distance + partial argmin (unchanged from R3, passing) ----------------
__global__ __launch_bounds__(256, 2)
void dist_mfma(const uint32_t* __restrict__ rp, const uint32_t* __restrict__ ep,
               const float* __restrict__ esq,
               float* __restrict__ pbD, int* __restrict__ pbI,
               int N, int vtPB) {
    __shared__ short Ah[128 * LDST];
    __shared__ short Al[128 * LDST];
    __shared__ short Bb[128 * LDST];

    const int tid  = threadIdx.x;
    const int wave = tid >> 6, lane = tid & 63;
    const int quad = lane >> 4, l15 = lane & 15;
    const int qh = wave & 1, vh = wave >> 1;
    const int qb0 = blockIdx.x * 128;
    const int vslices = gridDim.y;
    const int vbase = blockIdx.y * vtPB * 128;

    float bD[4][4];
    int   bI[4][4];
#pragma unroll
    for (int ti = 0; ti < 4; ti++)
#pragma unroll
        for (int r = 0; r < 4; r++) { bD[ti][r] = INFINITY; bI[ti][r] = 0; }

    const int sq = tid >> 1;
    const int jg = (tid & 1) * 32;

    for (int vt = 0; vt < vtPB; vt++) {
        int v0 = vbase + vt * 128;
        floatx4 acc[4][4];
        floatx4 z = {0.f, 0.f, 0.f, 0.f};
#pragma unroll
        for (int ti = 0; ti < 4; ti++)
#pragma unroll
            for (int tj = 0; tj < 4; tj++) acc[ti][tj] = z;

        for (int kp = 0; kp < 2; kp++) {
            __syncthreads();
            {
                const uint32_t* src = rp + (size_t)(qb0 + sq) * CC + kp * 64 + jg;
                uint32_t* wh = (uint32_t*)&Ah[sq * LDST + jg];
                uint32_t* wl = (uint32_t*)&Al[sq * LDST + jg];
#pragma unroll
                for (int j = 0; j < 32; j += 2) {
                    uint32_t p0 = src[j], p1 = src[j + 1];
                    wh[j >> 1] = (p0 >> 16) | (p1 & 0xffff0000u);
                    wl[j >> 1] = (p0 & 0xffffu) | (p1 << 16);
                }
            }
            for (int bsel = 0; bsel < 2; bsel++) {
                if (bsel) __syncthreads();
                {
                    const uint32_t* src = ep + (size_t)(v0 + sq) * CC + kp * 64 + jg;
                    uint32_t* wb = (uint32_t*)&Bb[sq * LDST + jg];
#pragma unroll
                    for (int j = 0; j < 32; j += 2) {
                        uint32_t p0 = src[j], p1 = src[j + 1];
                        uint32_t h0 = bsel ? (p0 & 0xffffu) : (p0 >> 16);
                        uint32_t h1 = bsel ? (p1 & 0xffffu) : (p1 >> 16);
                        wb[j >> 1] = h0 | (h1 << 16);
                    }
                }
                __syncthreads();
#pragma unroll
                for (int ks = 0; ks < 2; ks++) {
                    const int ko = ks * 32 + quad * 8;
                    short8 av[4], aw[4], bv[4];
#pragma unroll
                    for (int ti = 0; ti < 4; ti++)
                        av[ti] = *(const short8*)&Ah[(qh * 64 + ti * 16 + l15) * LDST + ko];
#pragma unroll
                    for (int ti = 0; ti < 4; ti++)
                        aw[ti] = *(const short8*)&Al[(qh * 64 + ti * 16 + l15) * LDST + ko];
#pragma unroll
                    for (int tj = 0; tj < 4; tj++)
                        bv[tj] = *(const short8*)&Bb[(vh * 64 + tj * 16 + l15) * LDST + ko];
#pragma unroll
                    for (int ti = 0; ti < 4; ti++)
#pragma unroll
                        for (int tj = 0; tj < 4; tj++) {
                            acc[ti][tj] = __builtin_amdgcn_mfma_f32_16x16x32_bf16(
                                av[ti], bv[tj], acc[ti][tj], 0, 0, 0);
                            acc[ti][tj] = __builtin_amdgcn_mfma_f32_16x16x32_bf16(
                                aw[ti], bv[tj], acc[ti][tj], 0, 0, 0);
                        }
                }
            }
        }

#pragma unroll
        for (int tj = 0; tj < 4; tj++) {
            int vg = v0 + vh * 64 + tj * 16 + l15;
            float ev = esq[vg];
#pragma unroll
            for (int ti = 0; ti < 4; ti++)
#pragma unroll
                for (int r = 0; r < 4; r++) {
                    float d = fmaf(-2.f, acc[ti][tj][r], ev);
                    if (d < bD[ti][r]) { bD[ti][r] = d; bI[ti][r] = vg; }
                }
        }
    }

#pragma unroll
    for (int ti = 0; ti < 4; ti++)
#pragma unroll
        for (int r = 0; r < 4; r++) {
            float d = bD[ti][r];
            int   v = bI[ti][r];
#pragma unroll
            for (int m = 1; m <= 8; m <<= 1) {
                float od = __shfl_xor(d, m, 64);
                int   ov = __shfl_xor(v, m, 64);
                if (od < d || (od == d && ov < v)) { d = od; v = ov; }
            }
            if (l15 == 0) {
                int q = qb0 + qh * 64 + ti * 16 + quad * 4 + r;
                if (q < N) {
                    size_t o = (size_t)q * (vslices * 2) + blockIdx.y * 2 + vh;
                    pbD[o] = d;
                    pbI[o] = v;
                }
            }
        }
}

// ---------------- final argmin across partials ----------------
__global__ void argmin_reduce(const float* __restrict__ pbD, const int* __restrict__ pbI,
                              int* __restrict__ idx, int N, int vsplit) {
    int q = blockIdx.x * blockDim.x + threadIdx.x;
    if (q >= N) return;
    float bd = pbD[(size_t)q * vsplit];
    int   bi = pbI[(size_t)q * vsplit];
    for (int j = 1; j < vsplit; j++) {
        float d  = pbD[(size_t)q * vsplit + j];
        int   i2 = pbI[(size_t)q * vsplit + j];
        if (d < bd || (d == bd && i2 < bi)) { bd = d; bi = i2; }
    }
    idx[q] = bi;
}

// ---------------- Keys cubic a=-0.5 (matches jax) ----------------
__device__ __forceinline__ float cubic_k(float x) {
    if (x <= 1.f) return (1.5f * x - 2.5f) * x * x + 1.f;
    if (x < 2.f)  return ((-0.5f * x + 2.5f) * x - 4.f) * x + 2.f;
    return 0.f;
}

// ---------------- upsample codes -> h: fp32 channel-first + padded hi/lo bf16 channel-last ----
// grid = (32 b * 16 cig), 256 threads = pixel; each thread does 8 channels.
template <int PN>
__global__ __launch_bounds__(256)
void upsample_pack(const float* __restrict__ emb, const int* __restrict__ idx,
                   short* __restrict__ hhi, short* __restrict__ hlo,
                   float* __restrict__ hfp) {
    const int t = threadIdx.x;
    const int x = t & 15, y = t >> 4;
    const int b = blockIdx.x >> 4;
    const int c0 = (blockIdx.x & 15) * 8;

    float val[8];

    if (PN == 16) {
        int id = idx[b * 256 + t];
        float4 v0 = *(const float4*)(emb + (size_t)id * CC + c0);
        float4 v1 = *(const float4*)(emb + (size_t)id * CC + c0 + 4);
        val[0]=v0.x; val[1]=v0.y; val[2]=v0.z; val[3]=v0.w;
        val[4]=v1.x; val[5]=v1.y; val[6]=v1.z; val[7]=v1.w;
    } else {
        __shared__ int idxL[PN * PN];
        __shared__ float S[PN * PN][8];
        if (t < PN * PN) idxL[t] = idx[b * PN * PN + t];
        __syncthreads();
        if (t < PN * PN) {
            float4 v0 = *(const float4*)(emb + (size_t)idxL[t] * CC + c0);
            float4 v1 = *(const float4*)(emb + (size_t)idxL[t] * CC + c0 + 4);
            S[t][0]=v0.x; S[t][1]=v0.y; S[t][2]=v0.z; S[t][3]=v0.w;
            S[t][4]=v1.x; S[t][5]=v1.y; S[t][6]=v1.z; S[t][7]=v1.w;
        }
        __syncthreads();

        const float sc = (float)PN / 16.f;
        float sy = (y + 0.5f) * sc - 0.5f;
        float sx = (x + 0.5f) * sc - 0.5f;
        int iy0 = (int)floorf(sy) - 1;
        int ix0 = (int)floorf(sx) - 1;
        float wy[4], wx[4];
        float ssy = 0.f, ssx = 0.f;
#pragma unroll
        for (int k = 0; k < 4; k++) {
            int iy = iy0 + k, ix = ix0 + k;
            float a = (iy >= 0 && iy < PN) ? cubic_k(fabsf(sy - (float)iy)) : 0.f;
            float bb = (ix >= 0 && ix < PN) ? cubic_k(fabsf(sx - (float)ix)) : 0.f;
            wy[k] = a; ssy += a;
            wx[k] = bb; ssx += bb;
        }
        float ry = 1.f / ssy, rx = 1.f / ssx;
#pragma unroll
        for (int k = 0; k < 4; k++) { wy[k] *= ry; wx[k] *= rx; }

#pragma unroll
        for (int j = 0; j < 8; j++) val[j] = 0.f;
#pragma unroll
        for (int k4 = 0; k4 < 4; k4++) {
            int iy = iy0 + k4;
            if (iy < 0 || iy >= PN) continue;
#pragma unroll
            for (int j4 = 0; j4 < 4; j4++) {
                int ix = ix0 + j4;
                if (ix < 0 || ix >= PN) continue;
                float w = wy[k4] * wx[j4];
                const float* sp = S[iy * PN + ix];
#pragma unroll
                for (int j = 0; j < 8; j++) val[j] = fmaf(w, sp[j], val[j]);
            }
        }
    }

    short hs[8], ls[8];
#pragma unroll
    for (int j = 0; j < 8; j++) {
        uint32_t u = pack_hilo(val[j]);
        hs[j] = (short)(u >> 16);
        ls[j] = (short)(u & 0xffffu);
    }
    size_t ho = ((size_t)(b * 18 + y + 1) * 18 + (x + 1)) * CC + c0;
    *(short8*)(hhi + ho) = *(short8*)hs;
    *(short8*)(hlo + ho) = *(short8*)ls;
#pragma unroll
    for (int j = 0; j < 8; j++)
        hfp[((size_t)b * CC + c0 + j) * 256 + t] = val[j];
}

// ---------------- MFMA conv3x3 + phi + f_hat update + loss ----------------
// grid = 128 (32 b * 4 quarters of 64 px), 4 waves; wave = 16 px x 128 couts.
// A streamed from padded hi/lo planes, B from pre-transposed weight planes (L2).
__global__ __launch_bounds__(256)
void conv_mfma(const short* __restrict__ Whi, const short* __restrict__ Wlo,
               const short* __restrict__ hhi, const short* __restrict__ hlo,
               const float* __restrict__ hfp, const float* __restrict__ pb,
               const float* __restrict__ f, float* __restrict__ f_hat,
               float* __restrict__ lacc, int kphi) {
    __shared__ float lred[4];
    const int t = threadIdx.x;
    const int wave = t >> 6, lane = t & 63;
    const int quad = lane >> 4, l15 = lane & 15;
    const int b = blockIdx.x >> 2, quarter = blockIdx.x & 3;
    const int ptile = quarter * 64 + wave * 16;
    const int pa = ptile + l15;               // A-row pixel for this lane
    const int ya = pa >> 4, xa = pa & 15;

    floatx4 acc[8];
    floatx4 z = {0.f, 0.f, 0.f, 0.f};
#pragma unroll
    for (int nt = 0; nt < 8; nt++) acc[nt] = z;

    for (int kk = 0; kk < 9; kk++) {
        const int ky = kk / 3, kx = kk % 3;
        const size_t aoff = ((size_t)(b * 18 + ya + ky) * 18 + (xa + kx)) * CC + quad * 8;
        const size_t woff = ((size_t)(kphi * 9 + kk) * CC + l15) * CC + quad * 8;
#pragma unroll
        for (int cic = 0; cic < 4; cic++) {
            short8 ah = *(const short8*)(hhi + aoff + cic * 32);
            short8 al = *(const short8*)(hlo + aoff + cic * 32);
            short8 bh[8], bl[8];
#pragma unroll
            for (int nt = 0; nt < 8; nt++) {
                bh[nt] = *(const short8*)(Whi + woff + (size_t)nt * 16 * CC + cic * 32);
                bl[nt] = *(const short8*)(Wlo + woff + (size_t)nt * 16 * CC + cic * 32);
            }
#pragma unroll
            for (int nt = 0; nt < 8; nt++)
                acc[nt] = __builtin_amdgcn_mfma_f32_16x16x32_bf16(ah, bh[nt], acc[nt], 0, 0, 0);
#pragma unroll
            for (int nt = 0; nt < 8; nt++)
                acc[nt] = __builtin_amdgcn_mfma_f32_16x16x32_bf16(al, bh[nt], acc[nt], 0, 0, 0);
#pragma unroll
            for (int nt = 0; nt < 8; nt++)
                acc[nt] = __builtin_amdgcn_mfma_f32_16x16x32_bf16(ah, bl[nt], acc[nt], 0, 0, 0);
        }
    }

    // epilogue: D row = pixel (quad*4+r), col = cout (l15)  [m89 C/D layout]
    const int pe = ptile + quad * 4;
    float lsum = 0.f;
#pragma unroll
    for (int nt = 0; nt < 8; nt++) {
        int cout = nt * 16 + l15;
        float bias = pb[kphi * CC + cout];
        size_t gi = ((size_t)b * CC + cout) * 256 + pe;
        float4 h4  = *(const float4*)(hfp + gi);
        float4 fh4 = *(const float4*)(f_hat + gi);
        float4 f4  = *(const float4*)(f + gi);
        float o0 = fh4.x + 0.5f * h4.x + 0.5f * (acc[nt][0] + bias);
        float o1 = fh4.y + 0.5f * h4.y + 0.5f * (acc[nt][1] + bias);
        float o2 = fh4.z + 0.5f * h4.z + 0.5f * (acc[nt][2] + bias);
        float o3 = fh4.w + 0.5f * h4.w + 0.5f * (acc[nt][3] + bias);
        float4 o = make_float4(o0, o1, o2, o3);
        *(float4*)(f_hat + gi) = o;
        float d0 = o0 - f4.x, d1 = o1 - f4.y, d2 = o2 - f4.z, d3 = o3 - f4.w;
        lsum += d0*d0 + d1*d1 + d2*d2 + d3*d3;
    }
#pragma unroll
    for (int off = 32; off; off >>= 1) lsum += __shfl_down(lsum, off, 64);
    if ((t & 63) == 0) lred[t >> 6] = lsum;
    __syncthreads();
    if (t == 0) atomicAdd(lacc, lred[0] + lred[1] + lred[2] + lred[3]);
}

__global__ void finalize_kernel(const float* __restrict__ lacc, float* __restrict__ out_loss) {
    *out_loss = lacc[0] * (0.25f / (float)NELEM);   // (1+BETA)/SN * sum of means
}

extern "C" void kernel_launch(void* const* d_in, const int* in_sizes, int n_in,
                              void* d_out, int out_size, void* d_ws, size_t ws_size,
                              hipStream_t stream) {
    const float* f   = (const float*)d_in[0];
    const float* emb = (const float*)d_in[1];
    const float* pw  = (const float*)d_in[2];
    const float* pb  = (const float*)d_in[3];
    float* out = (float*)d_out;

    uint32_t* w32   = (uint32_t*)d_ws;
    uint32_t* rpack = w32;                          // 1,048,576 u32
    uint32_t* epack = w32 + 1048576;                // 1,048,576 u32
    short*    Whi   = (short*)(w32 + 2097152);      // 589,824 shorts (294,912 u32)
    short*    Wlo   = (short*)(w32 + 2392064);      // 589,824 shorts
    short*    hhi   = (short*)(w32 + 2686976);      // 1,327,104 shorts (663,552 u32)
    short*    hlo   = (short*)(w32 + 3350528);      // 1,327,104 shorts
    float*    hfp   = (float*)(w32 + 4014080);      // 1,048,576
    float*    esq   = (float*)(w32 + 5062656);      // 8192
    int*      idx   = (int*)  (w32 + 5070848);      // 8192
    float*    pbD   = (float*)(w32 + 5079040);      // 131072
    int*      pbI   = (int*)  (w32 + 5210112);      // 131072
    float*    lacc  = (float*)(w32 + 5341184);      // 1

    hipMemsetAsync(d_out, 0, (size_t)NELEM * sizeof(float), stream);  // f_hat = 0
    hipMemsetAsync(lacc, 0, sizeof(float), stream);
    hipMemsetAsync(hhi, 0, (size_t)2 * 1327104 * sizeof(short), stream);  // zero borders (hhi+hlo)

    esq_kernel<<<VV / 256, 256, 0, stream>>>(emb, esq);
    prepack_emb<<<(VV * 32) / 256, 256, 0, stream>>>(emb, epack);
    prepack_w<<<65536 / 256, 256, 0, stream>>>(pw, Whi, Wlo);

    // mirror np.linspace(1/12, 11/12, 4) exactly in float64
    double start = 1.0 / 12.0;
    double stop  = 1.0 - 1.0 / 12.0;
    double step  = (stop - start) / 3.0;
    double ticks[4] = {start, 1.0 * step + start, 2.0 * step + start, stop};

    const int pns[5]    = {1, 2, 4, 8, 16};
    const int gridy5[5] = {64, 64, 32, 16, 8};      // vslices
    const int vtPB5[5]  = {1, 1, 2, 4, 8};          // vtiles per block

    for (int si = 0; si < 5; si++) {
        int pn = pns[si];
        int N  = BB * pn * pn;
        double tt = (double)si / 4.0;
        int kphi = 0;
        double bd = fabs(ticks[0] - tt);
        for (int i = 1; i < 4; i++) {
            double d = fabs(ticks[i] - tt);
            if (d < bd) { bd = d; kphi = i; }   // np.argmin: first occurrence
        }

        pool_pack<<<(N * CC) / 256, 256, 0, stream>>>(f, out, rpack, pn);

        int qb = (N + 127) / 128;
        dim3 dgrid(qb, gridy5[si]);
        dist_mfma<<<dgrid, 256, 0, stream>>>(rpack, epack, esq, pbD, pbI, N, vtPB5[si]);
        argmin_reduce<<<(N + 255) / 256, 256, 0, stream>>>(pbD, pbI, idx, N, gridy5[si] * 2);

        switch (pn) {
            case 1:  upsample_pack<1><<<512, 256, 0, stream>>>(emb, idx, hhi, hlo, hfp); break;
            case 2:  upsample_pack<2><<<512, 256, 0, stream>>>(emb, idx, hhi, hlo, hfp); break;
            case 4:  upsample_pack<4><<<512, 256, 0, stream>>>(emb, idx, hhi, hlo, hfp); break;
            case 8:  upsample_pack<8><<<512, 256, 0, stream>>>(emb, idx, hhi, hlo, hfp); break;
            default: upsample_pack<16><<<512, 256, 0, stream>>>(emb, idx, hhi, hlo, hfp); break;
        }

        conv_mfma<<<128, 256, 0, stream>>>(Whi, Wlo, hhi, hlo, hfp, pb, f, out, lacc, kphi);
    }

    finalize_kernel<<<1, 1, 0, stream>>>(lacc, out + NELEM);
}

// Round 5
// 633.064 us; speedup vs baseline: 2.6046x; 1.5279x over previous
//
#include <hip/hip_runtime.h>
#include <math.h>

#define CC   128
#define HH   16
#define WW   16
#define BB   32
#define VV   8192
#define NELEM (BB*CC*HH*WW)   // 1,048,576

typedef short short8 __attribute__((ext_vector_type(8)));
typedef float floatx4 __attribute__((ext_vector_type(4)));

#define LDST 72    // dist LDS row stride in bf16 elems (64 + 8 pad)
#define CSTR 136   // conv LDS row stride in bf16 elems (128 + 8 pad)

// ---------------- hi/lo bf16 split pack (RNE both) ----------------
__device__ __forceinline__ uint32_t pack_hilo(float x) {
    uint32_t u = __float_as_uint(x);
    uint32_t hb = (u + 0x7fffu + ((u >> 16) & 1u)) & 0xffff0000u;
    float hf = __uint_as_float(hb);
    float lo = x - hf;
    uint32_t ul = __float_as_uint(lo);
    uint32_t lb = ((ul + 0x7fffu + ((ul >> 16) & 1u)) >> 16) & 0xffffu;
    return hb | lb;
}

// ---------------- e_sq ----------------
__global__ void esq_kernel(const float* __restrict__ emb, float* __restrict__ esq) {
    int v = blockIdx.x * blockDim.x + threadIdx.x;
    const float* row = emb + (size_t)v * CC;
    float s = 0.f;
#pragma unroll
    for (int c = 0; c < CC; c += 4) {
        float4 e4 = *(const float4*)(row + c);
        s += e4.x*e4.x + e4.y*e4.y + e4.z*e4.z + e4.w*e4.w;
    }
    esq[v] = s;
}

// ---------------- pack codebook to hi|lo u32 ----------------
__global__ void prepack_emb(const float* __restrict__ emb, uint32_t* __restrict__ ep) {
    int id = blockIdx.x * 256 + threadIdx.x;
    int g = id % 32, v = id / 32;
    float4 e4 = *(const float4*)(emb + (size_t)v * CC + g * 4);
    uint4 o;
    o.x = pack_hilo(e4.x); o.y = pack_hilo(e4.y);
    o.z = pack_hilo(e4.z); o.w = pack_hilo(e4.w);
    *(uint4*)(ep + (size_t)v * CC + g * 4) = o;
}

// ---------------- pre-transpose + split conv weights: Wt[kphi][kk][cout][cin] ----------------
__global__ void prepack_w(const float* __restrict__ pw, short* __restrict__ Whi,
                          short* __restrict__ Wlo) {
    int id = blockIdx.x * 256 + threadIdx.x;      // 65536 = 4*128*128
    int ci = id & 127, cout = (id >> 7) & 127, kp = id >> 14;
    const float* src = pw + ((size_t)(kp * CC + cout) * CC + ci) * 9;
#pragma unroll
    for (int kk = 0; kk < 9; kk++) {
        uint32_t u = pack_hilo(src[kk]);
        size_t o = ((size_t)(kp * 9 + kk) * CC + cout) * CC + ci;
        Whi[o] = (short)(u >> 16);
        Wlo[o] = (short)(u & 0xffffu);
    }
}

// ---------------- pooled residual (f - f_hat), packed hi|lo ----------------
__global__ void pool_pack(const float* __restrict__ f, const float* __restrict__ fh,
                          uint32_t* __restrict__ rp, int pn) {
    int id = blockIdx.x * 256 + threadIdx.x;
    int c = id % CC;
    int n = id / CC;
    int px = n % pn;
    int py = (n / pn) % pn;
    int b  = n / (pn * pn);
    int s  = HH / pn;
    size_t o = (((size_t)b * CC + c) * HH + py * s) * WW + px * s;
    float acc = 0.f;
    for (int dy = 0; dy < s; dy++)
        for (int dx = 0; dx < s; dx++)
            acc += f[o + dy * WW + dx] - fh[o + dy * WW + dx];
    rp[id] = pack_hilo(acc * (1.f / (float)(s * s)));
}

// ---------------- MFMA distance + partial argmin (unchanged control) ----------------
__global__ __launch_bounds__(256, 2)
void dist_mfma(const uint32_t* __restrict__ rp, const uint32_t* __restrict__ ep,
               const float* __restrict__ esq,
               float* __restrict__ pbD, int* __restrict__ pbI,
               int N, int vtPB) {
    __shared__ short Ah[128 * LDST];
    __shared__ short Al[128 * LDST];
    __shared__ short Bb[128 * LDST];

    const int tid  = threadIdx.x;
    const int wave = tid >> 6, lane = tid & 63;
    const int quad = lane >> 4, l15 = lane & 15;
    const int qh = wave & 1, vh = wave >> 1;
    const int qb0 = blockIdx.x * 128;
    const int vslices = gridDim.y;
    const int vbase = blockIdx.y * vtPB * 128;

    float bD[4][4];
    int   bI[4][4];
#pragma unroll
    for (int ti = 0; ti < 4; ti++)
#pragma unroll
        for (int r = 0; r < 4; r++) { bD[ti][r] = INFINITY; bI[ti][r] = 0; }

    const int sq = tid >> 1;
    const int jg = (tid & 1) * 32;

    for (int vt = 0; vt < vtPB; vt++) {
        int v0 = vbase + vt * 128;
        floatx4 acc[4][4];
        floatx4 z = {0.f, 0.f, 0.f, 0.f};
#pragma unroll
        for (int ti = 0; ti < 4; ti++)
#pragma unroll
            for (int tj = 0; tj < 4; tj++) acc[ti][tj] = z;

        for (int kp = 0; kp < 2; kp++) {
            __syncthreads();
            {
                const uint32_t* src = rp + (size_t)(qb0 + sq) * CC + kp * 64 + jg;
                uint32_t* wh = (uint32_t*)&Ah[sq * LDST + jg];
                uint32_t* wl = (uint32_t*)&Al[sq * LDST + jg];
#pragma unroll
                for (int j = 0; j < 32; j += 2) {
                    uint32_t p0 = src[j], p1 = src[j + 1];
                    wh[j >> 1] = (p0 >> 16) | (p1 & 0xffff0000u);
                    wl[j >> 1] = (p0 & 0xffffu) | (p1 << 16);
                }
            }
            for (int bsel = 0; bsel < 2; bsel++) {
                if (bsel) __syncthreads();
                {
                    const uint32_t* src = ep + (size_t)(v0 + sq) * CC + kp * 64 + jg;
                    uint32_t* wb = (uint32_t*)&Bb[sq * LDST + jg];
#pragma unroll
                    for (int j = 0; j < 32; j += 2) {
                        uint32_t p0 = src[j], p1 = src[j + 1];
                        uint32_t h0 = bsel ? (p0 & 0xffffu) : (p0 >> 16);
                        uint32_t h1 = bsel ? (p1 & 0xffffu) : (p1 >> 16);
                        wb[j >> 1] = h0 | (h1 << 16);
                    }
                }
                __syncthreads();
#pragma unroll
                for (int ks = 0; ks < 2; ks++) {
                    const int ko = ks * 32 + quad * 8;
                    short8 av[4], aw[4], bv[4];
#pragma unroll
                    for (int ti = 0; ti < 4; ti++)
                        av[ti] = *(const short8*)&Ah[(qh * 64 + ti * 16 + l15) * LDST + ko];
#pragma unroll
                    for (int ti = 0; ti < 4; ti++)
                        aw[ti] = *(const short8*)&Al[(qh * 64 + ti * 16 + l15) * LDST + ko];
#pragma unroll
                    for (int tj = 0; tj < 4; tj++)
                        bv[tj] = *(const short8*)&Bb[(vh * 64 + tj * 16 + l15) * LDST + ko];
#pragma unroll
                    for (int ti = 0; ti < 4; ti++)
#pragma unroll
                        for (int tj = 0; tj < 4; tj++) {
                            acc[ti][tj] = __builtin_amdgcn_mfma_f32_16x16x32_bf16(
                                av[ti], bv[tj], acc[ti][tj], 0, 0, 0);
                            acc[ti][tj] = __builtin_amdgcn_mfma_f32_16x16x32_bf16(
                                aw[ti], bv[tj], acc[ti][tj], 0, 0, 0);
                        }
                }
            }
        }

#pragma unroll
        for (int tj = 0; tj < 4; tj++) {
            int vg = v0 + vh * 64 + tj * 16 + l15;
            float ev = esq[vg];
#pragma unroll
            for (int ti = 0; ti < 4; ti++)
#pragma unroll
                for (int r = 0; r < 4; r++) {
                    float d = fmaf(-2.f, acc[ti][tj][r], ev);
                    if (d < bD[ti][r]) { bD[ti][r] = d; bI[ti][r] = vg; }
                }
        }
    }

#pragma unroll
    for (int ti = 0; ti < 4; ti++)
#pragma unroll
        for (int r = 0; r < 4; r++) {
            float d = bD[ti][r];
            int   v = bI[ti][r];
#pragma unroll
            for (int m = 1; m <= 8; m <<= 1) {
                float od = __shfl_xor(d, m, 64);
                int   ov = __shfl_xor(v, m, 64);
                if (od < d || (od == d && ov < v)) { d = od; v = ov; }
            }
            if (l15 == 0) {
                int q = qb0 + qh * 64 + ti * 16 + quad * 4 + r;
                if (q < N) {
                    size_t o = (size_t)q * (vslices * 2) + blockIdx.y * 2 + vh;
                    pbD[o] = d;
                    pbI[o] = v;
                }
            }
        }
}

// ---------------- final argmin across partials ----------------
__global__ void argmin_reduce(const float* __restrict__ pbD, const int* __restrict__ pbI,
                              int* __restrict__ idx, int N, int vsplit) {
    int q = blockIdx.x * blockDim.x + threadIdx.x;
    if (q >= N) return;
    float bd = pbD[(size_t)q * vsplit];
    int   bi = pbI[(size_t)q * vsplit];
    for (int j = 1; j < vsplit; j++) {
        float d  = pbD[(size_t)q * vsplit + j];
        int   i2 = pbI[(size_t)q * vsplit + j];
        if (d < bd || (d == bd && i2 < bi)) { bd = d; bi = i2; }
    }
    idx[q] = bi;
}

// ---------------- Keys cubic a=-0.5 (matches jax) ----------------
__device__ __forceinline__ float cubic_k(float x) {
    if (x <= 1.f) return (1.5f * x - 2.5f) * x * x + 1.f;
    if (x < 2.f)  return ((-0.5f * x + 2.5f) * x - 4.f) * x + 2.f;
    return 0.f;
}

// ---------------- upsample codes -> h: fp32 channel-first + padded hi/lo bf16 channel-last ----
template <int PN>
__global__ __launch_bounds__(256)
void upsample_pack(const float* __restrict__ emb, const int* __restrict__ idx,
                   short* __restrict__ hhi, short* __restrict__ hlo,
                   float* __restrict__ hfp) {
    const int t = threadIdx.x;
    const int x = t & 15, y = t >> 4;
    const int b = blockIdx.x >> 4;
    const int c0 = (blockIdx.x & 15) * 8;

    float val[8];

    if (PN == 16) {
        int id = idx[b * 256 + t];
        float4 v0 = *(const float4*)(emb + (size_t)id * CC + c0);
        float4 v1 = *(const float4*)(emb + (size_t)id * CC + c0 + 4);
        val[0]=v0.x; val[1]=v0.y; val[2]=v0.z; val[3]=v0.w;
        val[4]=v1.x; val[5]=v1.y; val[6]=v1.z; val[7]=v1.w;
    } else {
        __shared__ int idxL[PN * PN];
        __shared__ float S[PN * PN][8];
        if (t < PN * PN) idxL[t] = idx[b * PN * PN + t];
        __syncthreads();
        if (t < PN * PN) {
            float4 v0 = *(const float4*)(emb + (size_t)idxL[t] * CC + c0);
            float4 v1 = *(const float4*)(emb + (size_t)idxL[t] * CC + c0 + 4);
            S[t][0]=v0.x; S[t][1]=v0.y; S[t][2]=v0.z; S[t][3]=v0.w;
            S[t][4]=v1.x; S[t][5]=v1.y; S[t][6]=v1.z; S[t][7]=v1.w;
        }
        __syncthreads();

        const float sc = (float)PN / 16.f;
        float sy = (y + 0.5f) * sc - 0.5f;
        float sx = (x + 0.5f) * sc - 0.5f;
        int iy0 = (int)floorf(sy) - 1;
        int ix0 = (int)floorf(sx) - 1;
        float wy[4], wx[4];
        float ssy = 0.f, ssx = 0.f;
#pragma unroll
        for (int k = 0; k < 4; k++) {
            int iy = iy0 + k, ix = ix0 + k;
            float a = (iy >= 0 && iy < PN) ? cubic_k(fabsf(sy - (float)iy)) : 0.f;
            float bb = (ix >= 0 && ix < PN) ? cubic_k(fabsf(sx - (float)ix)) : 0.f;
            wy[k] = a; ssy += a;
            wx[k] = bb; ssx += bb;
        }
        float ry = 1.f / ssy, rx = 1.f / ssx;
#pragma unroll
        for (int k = 0; k < 4; k++) { wy[k] *= ry; wx[k] *= rx; }

#pragma unroll
        for (int j = 0; j < 8; j++) val[j] = 0.f;
#pragma unroll
        for (int k4 = 0; k4 < 4; k4++) {
            int iy = iy0 + k4;
            if (iy < 0 || iy >= PN) continue;
#pragma unroll
            for (int j4 = 0; j4 < 4; j4++) {
                int ix = ix0 + j4;
                if (ix < 0 || ix >= PN) continue;
                float w = wy[k4] * wx[j4];
                const float* sp = S[iy * PN + ix];
#pragma unroll
                for (int j = 0; j < 8; j++) val[j] = fmaf(w, sp[j], val[j]);
            }
        }
    }

    short hs[8], ls[8];
#pragma unroll
    for (int j = 0; j < 8; j++) {
        uint32_t u = pack_hilo(val[j]);
        hs[j] = (short)(u >> 16);
        ls[j] = (short)(u & 0xffffu);
    }
    size_t ho = ((size_t)(b * 18 + y + 1) * 18 + (x + 1)) * CC + c0;
    *(short8*)(hhi + ho) = *(short8*)hs;
    *(short8*)(hlo + ho) = *(short8*)ls;
#pragma unroll
    for (int j = 0; j < 8; j++)
        hfp[((size_t)b * CC + c0 + j) * 256 + t] = val[j];
}

// ---------------- MFMA conv3x3 v2: LDS-shared weights, K-split ----------------
// grid = 512: cH = blk&1 (cout half), pc = blk>>1: b = pc>>3, pxbase = (pc&7)*32.
// 4 waves: pxg = w&1 (16 px), kh = w>>1 (cic half). Wave: 16 px x 64 cout.
__global__ __launch_bounds__(256)
void conv_mfma(const short* __restrict__ Whi, const short* __restrict__ Wlo,
               const short* __restrict__ hhi, const short* __restrict__ hlo,
               const float* __restrict__ hfp, const float* __restrict__ pb,
               const float* __restrict__ f, float* __restrict__ f_hat,
               float* __restrict__ lacc, int kphi) {
    __shared__ short Bsh[64 * CSTR];
    __shared__ short Bsl[64 * CSTR];
    __shared__ float red[2][16][65];
    __shared__ float lred[2];

    const int t = threadIdx.x;
    const int wave = t >> 6, lane = t & 63;
    const int quad = lane >> 4, l15 = lane & 15;
    const int pxg = wave & 1, kh = wave >> 1;
    const int cH = blockIdx.x & 1;
    const int pc = blockIdx.x >> 1;
    const int b = pc >> 3;
    const int pxbase = (pc & 7) * 32;
    const int pa = pxbase + pxg * 16 + l15;     // this lane's A pixel
    const int ya = pa >> 4, xa = pa & 15;

    floatx4 acc[4];
    floatx4 z = {0.f, 0.f, 0.f, 0.f};
#pragma unroll
    for (int nt = 0; nt < 4; nt++) acc[nt] = z;

    for (int kk = 0; kk < 9; kk++) {
        __syncthreads();   // prior kk's ds_reads complete
        {   // stage W[kk] slice for this cout-half: 64 rows x 128 ci, hi+lo
            const short* gh = Whi + ((size_t)(kphi * 9 + kk) * CC + cH * 64) * CC;
            const short* gl = Wlo + ((size_t)(kphi * 9 + kk) * CC + cH * 64) * CC;
#pragma unroll
            for (int i = 0; i < 4; i++) {
                int chunk = i * 256 + t;
                int row = chunk >> 4, col = (chunk & 15) * 8;
                *(short8*)&Bsh[row * CSTR + col] = *(const short8*)(gh + row * CC + col);
                *(short8*)&Bsl[row * CSTR + col] = *(const short8*)(gl + row * CC + col);
            }
        }
        __syncthreads();

        const int ky = kk / 3, kx = kk % 3;
        const size_t aoff = ((size_t)(b * 18 + ya + ky) * 18 + (xa + kx)) * CC + quad * 8;
#pragma unroll
        for (int i2 = 0; i2 < 2; i2++) {
            const int cic = kh * 2 + i2;
            short8 ah = *(const short8*)(hhi + aoff + cic * 32);
            short8 al = *(const short8*)(hlo + aoff + cic * 32);
#pragma unroll
            for (int nt = 0; nt < 4; nt++) {
                short8 bh = *(const short8*)&Bsh[(nt * 16 + l15) * CSTR + cic * 32 + quad * 8];
                short8 bl = *(const short8*)&Bsl[(nt * 16 + l15) * CSTR + cic * 32 + quad * 8];
                acc[nt] = __builtin_amdgcn_mfma_f32_16x16x32_bf16(ah, bh, acc[nt], 0, 0, 0);
                acc[nt] = __builtin_amdgcn_mfma_f32_16x16x32_bf16(al, bh, acc[nt], 0, 0, 0);
                acc[nt] = __builtin_amdgcn_mfma_f32_16x16x32_bf16(ah, bl, acc[nt], 0, 0, 0);
            }
        }
    }

    __syncthreads();   // all ds_reads of Bsh/Bsl done; red reuse safe
    if (kh == 1) {
#pragma unroll
        for (int nt = 0; nt < 4; nt++)
#pragma unroll
            for (int r = 0; r < 4; r++)
                red[pxg][quad * 4 + r][nt * 16 + l15] = acc[nt][r];
    }
    __syncthreads();

    if (kh == 0) {
        const int pe = pxbase + pxg * 16 + quad * 4;
        float lsum = 0.f;
#pragma unroll
        for (int nt = 0; nt < 4; nt++) {
            int cout = cH * 64 + nt * 16 + l15;
            float bias = pb[kphi * CC + cout];
            size_t gi = ((size_t)b * CC + cout) * 256 + pe;
            float4 h4  = *(const float4*)(hfp + gi);
            float4 fh4 = *(const float4*)(f_hat + gi);
            float4 f4  = *(const float4*)(f + gi);
            float c0 = acc[nt][0] + red[pxg][quad * 4 + 0][nt * 16 + l15] + bias;
            float c1 = acc[nt][1] + red[pxg][quad * 4 + 1][nt * 16 + l15] + bias;
            float c2 = acc[nt][2] + red[pxg][quad * 4 + 2][nt * 16 + l15] + bias;
            float c3 = acc[nt][3] + red[pxg][quad * 4 + 3][nt * 16 + l15] + bias;
            float o0 = fh4.x + 0.5f * h4.x + 0.5f * c0;
            float o1 = fh4.y + 0.5f * h4.y + 0.5f * c1;
            float o2 = fh4.z + 0.5f * h4.z + 0.5f * c2;
            float o3 = fh4.w + 0.5f * h4.w + 0.5f * c3;
            *(float4*)(f_hat + gi) = make_float4(o0, o1, o2, o3);
            float d0 = o0 - f4.x, d1 = o1 - f4.y, d2 = o2 - f4.z, d3 = o3 - f4.w;
            lsum += d0*d0 + d1*d1 + d2*d2 + d3*d3;
        }
#pragma unroll
        for (int off = 32; off; off >>= 1) lsum += __shfl_down(lsum, off, 64);
        if (lane == 0) lred[pxg] = lsum;
    }
    __syncthreads();
    if (t == 0) atomicAdd(lacc, lred[0] + lred[1]);
}

__global__ void finalize_kernel(const float* __restrict__ lacc, float* __restrict__ out_loss) {
    *out_loss = lacc[0] * (0.25f / (float)NELEM);   // (1+BETA)/SN * sum of means
}

extern "C" void kernel_launch(void* const* d_in, const int* in_sizes, int n_in,
                              void* d_out, int out_size, void* d_ws, size_t ws_size,
                              hipStream_t stream) {
    const float* f   = (const float*)d_in[0];
    const float* emb = (const float*)d_in[1];
    const float* pw  = (const float*)d_in[2];
    const float* pb  = (const float*)d_in[3];
    float* out = (float*)d_out;

    uint32_t* w32   = (uint32_t*)d_ws;
    uint32_t* rpack = w32;                          // 1,048,576 u32
    uint32_t* epack = w32 + 1048576;                // 1,048,576 u32
    short*    Whi   = (short*)(w32 + 2097152);      // 589,824 shorts
    short*    Wlo   = (short*)(w32 + 2392064);      // 589,824 shorts
    short*    hhi   = (short*)(w32 + 2686976);      // 1,327,104 shorts
    short*    hlo   = (short*)(w32 + 3350528);      // 1,327,104 shorts
    float*    hfp   = (float*)(w32 + 4014080);      // 1,048,576
    float*    esq   = (float*)(w32 + 5062656);      // 8192
    int*      idx   = (int*)  (w32 + 5070848);      // 8192
    float*    pbD   = (float*)(w32 + 5079040);      // 131072
    int*      pbI   = (int*)  (w32 + 5210112);      // 131072
    float*    lacc  = (float*)(w32 + 5341184);      // 1

    hipMemsetAsync(d_out, 0, (size_t)NELEM * sizeof(float), stream);  // f_hat = 0
    hipMemsetAsync(lacc, 0, sizeof(float), stream);
    hipMemsetAsync(hhi, 0, (size_t)2 * 1327104 * sizeof(short), stream);  // zero halos

    esq_kernel<<<VV / 256, 256, 0, stream>>>(emb, esq);
    prepack_emb<<<(VV * 32) / 256, 256, 0, stream>>>(emb, epack);
    prepack_w<<<65536 / 256, 256, 0, stream>>>(pw, Whi, Wlo);

    // mirror np.linspace(1/12, 11/12, 4) exactly in float64
    double start = 1.0 / 12.0;
    double stop  = 1.0 - 1.0 / 12.0;
    double step  = (stop - start) / 3.0;
    double ticks[4] = {start, 1.0 * step + start, 2.0 * step + start, stop};

    const int pns[5]    = {1, 2, 4, 8, 16};
    const int gridy5[5] = {64, 64, 32, 16, 8};      // vslices
    const int vtPB5[5]  = {1, 1, 2, 4, 8};          // vtiles per block

    for (int si = 0; si < 5; si++) {
        int pn = pns[si];
        int N  = BB * pn * pn;
        double tt = (double)si / 4.0;
        int kphi = 0;
        double bd = fabs(ticks[0] - tt);
        for (int i = 1; i < 4; i++) {
            double d = fabs(ticks[i] - tt);
            if (d < bd) { bd = d; kphi = i; }   // np.argmin: first occurrence
        }

        pool_pack<<<(N * CC) / 256, 256, 0, stream>>>(f, out, rpack, pn);

        int qb = (N + 127) / 128;
        dim3 dgrid(qb, gridy5[si]);
        dist_mfma<<<dgrid, 256, 0, stream>>>(rpack, epack, esq, pbD, pbI, N, vtPB5[si]);
        argmin_reduce<<<(N + 255) / 256, 256, 0, stream>>>(pbD, pbI, idx, N, gridy5[si] * 2);

        switch (pn) {
            case 1:  upsample_pack<1><<<512, 256, 0, stream>>>(emb, idx, hhi, hlo, hfp); break;
            case 2:  upsample_pack<2><<<512, 256, 0, stream>>>(emb, idx, hhi, hlo, hfp); break;
            case 4:  upsample_pack<4><<<512, 256, 0, stream>>>(emb, idx, hhi, hlo, hfp); break;
            case 8:  upsample_pack<8><<<512, 256, 0, stream>>>(emb, idx, hhi, hlo, hfp); break;
            default: upsample_pack<16><<<512, 256, 0, stream>>>(emb, idx, hhi, hlo, hfp); break;
        }

        conv_mfma<<<512, 256, 0, stream>>>(Whi, Wlo, hhi, hlo, hfp, pb, f, out, lacc, kphi);
    }

    finalize_kernel<<<1, 1, 0, stream>>>(lacc, out + NELEM);
}

// Round 6
// 553.264 us; speedup vs baseline: 2.9802x; 1.1442x over previous
//
#include <hip/hip_runtime.h>
#include <math.h>

#define CC   128
#define HH   16
#define WW   16
#define BB   32
#define VV   8192
#define NELEM (BB*CC*HH*WW)   // 1,048,576

typedef short short8 __attribute__((ext_vector_type(8)));
typedef float floatx4 __attribute__((ext_vector_type(4)));

#define CSTR 136   // conv LDS row stride in bf16 elems (128 + 8 pad)

// ---------------- hi/lo bf16 split pack (RNE both) ----------------
__device__ __forceinline__ uint32_t pack_hilo(float x) {
    uint32_t u = __float_as_uint(x);
    uint32_t hb = (u + 0x7fffu + ((u >> 16) & 1u)) & 0xffff0000u;
    float hf = __uint_as_float(hb);
    float lo = x - hf;
    uint32_t ul = __float_as_uint(lo);
    uint32_t lb = ((ul + 0x7fffu + ((ul >> 16) & 1u)) >> 16) & 0xffffu;
    return hb | lb;
}

// ---------------- e_sq + codebook hi/lo plane split + lacc zero ----------------
// 131072 threads: 16 per codebook row.
__global__ void esq_pack(const float* __restrict__ emb, float* __restrict__ esq,
                         short* __restrict__ ephi, short* __restrict__ eplo,
                         float* __restrict__ lacc) {
    int t = blockIdx.x * 256 + threadIdx.x;
    int v = t >> 4, g = t & 15;
    const float* row = emb + (size_t)v * CC + g * 8;
    float4 a = *(const float4*)row;
    float4 b = *(const float4*)(row + 4);
    float s = a.x*a.x + a.y*a.y + a.z*a.z + a.w*a.w
            + b.x*b.x + b.y*b.y + b.z*b.z + b.w*b.w;
    s += __shfl_xor(s, 1, 64);
    s += __shfl_xor(s, 2, 64);
    s += __shfl_xor(s, 4, 64);
    s += __shfl_xor(s, 8, 64);
    if (g == 0) esq[v] = s;
    float vals[8] = {a.x, a.y, a.z, a.w, b.x, b.y, b.z, b.w};
    short hs[8], ls[8];
#pragma unroll
    for (int j = 0; j < 8; j++) {
        uint32_t u = pack_hilo(vals[j]);
        hs[j] = (short)(u >> 16);
        ls[j] = (short)(u & 0xffffu);
    }
    *(short8*)(ephi + (size_t)v * CC + g * 8) = *(short8*)hs;
    *(short8*)(eplo + (size_t)v * CC + g * 8) = *(short8*)ls;
    if (t == 0) lacc[0] = 0.f;
}

// ---------------- pre-transpose + split conv weights: Wt[kphi][kk][cout][cin] ----------------
__global__ void prepack_w(const float* __restrict__ pw, short* __restrict__ Whi,
                          short* __restrict__ Wlo) {
    int id = blockIdx.x * 256 + threadIdx.x;      // 65536 = 4*128*128
    int ci = id & 127, cout = (id >> 7) & 127, kp = id >> 14;
    const float* src = pw + ((size_t)(kp * CC + cout) * CC + ci) * 9;
#pragma unroll
    for (int kk = 0; kk < 9; kk++) {
        uint32_t u = pack_hilo(src[kk]);
        size_t o = ((size_t)(kp * 9 + kk) * CC + cout) * CC + ci;
        Whi[o] = (short)(u >> 16);
        Wlo[o] = (short)(u & 0xffffu);
    }
}

// ---------------- pooled residual (f - f_hat) -> hi/lo planes ----------------
template <bool FIRSTP>
__global__ void pool_pack(const float* __restrict__ f, const float* __restrict__ fh,
                          short* __restrict__ rh, short* __restrict__ rl, int pn) {
    int id = blockIdx.x * 256 + threadIdx.x;
    int c = id % CC;
    int n = id / CC;
    int px = n % pn;
    int py = (n / pn) % pn;
    int b  = n / (pn * pn);
    int s  = HH / pn;
    size_t o = (((size_t)b * CC + c) * HH + py * s) * WW + px * s;
    float acc = 0.f;
    for (int dy = 0; dy < s; dy++)
        for (int dx = 0; dx < s; dx++)
            acc += FIRSTP ? f[o + dy * WW + dx] : (f[o + dy * WW + dx] - fh[o + dy * WW + dx]);
    uint32_t u = pack_hilo(acc * (1.f / (float)(s * s)));
    rh[id] = (short)(u >> 16);
    rl[id] = (short)(u & 0xffffu);
}

// ---------------- MFMA distance v3: barrier-free, LDS-free, A in registers ----------------
// grid (qb, vslices); block 256 = 4 waves: qh=w&1, vh=w>>1. Wave: 64 q x 64 v quadrant.
__global__ __launch_bounds__(256, 2)
void dist_mfma(const short* __restrict__ rphi, const short* __restrict__ rplo,
               const short* __restrict__ ephi, const short* __restrict__ eplo,
               const float* __restrict__ esq,
               float* __restrict__ pbD, int* __restrict__ pbI,
               int N, int vtPB) {
    const int tid  = threadIdx.x;
    const int wave = tid >> 6, lane = tid & 63;
    const int quad = lane >> 4, l15 = lane & 15;
    const int qh = wave & 1, vh = wave >> 1;
    const int qb0 = blockIdx.x * 128;
    const int vslices = gridDim.y;
    const int vbase = blockIdx.y * vtPB * 128;

    // A fragments loaded once: rows may exceed N (garbage but finite; outputs guarded)
    short8 av[4][4], aw[4][4];
#pragma unroll
    for (int ti = 0; ti < 4; ti++) {
        const size_t arow = (size_t)(qb0 + qh * 64 + ti * 16 + l15) * CC + quad * 8;
#pragma unroll
        for (int kc = 0; kc < 4; kc++) {
            av[ti][kc] = *(const short8*)(rphi + arow + kc * 32);
            aw[ti][kc] = *(const short8*)(rplo + arow + kc * 32);
        }
    }

    float bD[4][4];
    int   bI[4][4];
#pragma unroll
    for (int ti = 0; ti < 4; ti++)
#pragma unroll
        for (int r = 0; r < 4; r++) { bD[ti][r] = INFINITY; bI[ti][r] = 0; }

    for (int vt = 0; vt < vtPB; vt++) {
        const int v0 = vbase + vt * 128;
        floatx4 acc[4][4];
        floatx4 z = {0.f, 0.f, 0.f, 0.f};
#pragma unroll
        for (int ti = 0; ti < 4; ti++)
#pragma unroll
            for (int tj = 0; tj < 4; tj++) acc[ti][tj] = z;

#pragma unroll
        for (int kc = 0; kc < 4; kc++) {
            short8 bh[4], bl[4];
#pragma unroll
            for (int tj = 0; tj < 4; tj++) {
                const size_t brow = (size_t)(v0 + vh * 64 + tj * 16 + l15) * CC + quad * 8;
                bh[tj] = *(const short8*)(ephi + brow + kc * 32);
                bl[tj] = *(const short8*)(eplo + brow + kc * 32);
            }
#pragma unroll
            for (int ti = 0; ti < 4; ti++)
#pragma unroll
                for (int tj = 0; tj < 4; tj++) {
                    acc[ti][tj] = __builtin_amdgcn_mfma_f32_16x16x32_bf16(av[ti][kc], bh[tj], acc[ti][tj], 0, 0, 0);
                    acc[ti][tj] = __builtin_amdgcn_mfma_f32_16x16x32_bf16(aw[ti][kc], bh[tj], acc[ti][tj], 0, 0, 0);
                    acc[ti][tj] = __builtin_amdgcn_mfma_f32_16x16x32_bf16(av[ti][kc], bl[tj], acc[ti][tj], 0, 0, 0);
                    acc[ti][tj] = __builtin_amdgcn_mfma_f32_16x16x32_bf16(aw[ti][kc], bl[tj], acc[ti][tj], 0, 0, 0);
                }
        }

        // dist = esq - 2*dot; v ascending over vt/tj per lane -> strict < keeps first min
#pragma unroll
        for (int tj = 0; tj < 4; tj++) {
            int vg = v0 + vh * 64 + tj * 16 + l15;
            float ev = esq[vg];
#pragma unroll
            for (int ti = 0; ti < 4; ti++)
#pragma unroll
                for (int r = 0; r < 4; r++) {
                    float d = fmaf(-2.f, acc[ti][tj][r], ev);
                    if (d < bD[ti][r]) { bD[ti][r] = d; bI[ti][r] = vg; }
                }
        }
    }

    // cross-lane reduce within 16-lane groups (same q, different v), tie -> lower v
#pragma unroll
    for (int ti = 0; ti < 4; ti++)
#pragma unroll
        for (int r = 0; r < 4; r++) {
            float d = bD[ti][r];
            int   v = bI[ti][r];
#pragma unroll
            for (int m = 1; m <= 8; m <<= 1) {
                float od = __shfl_xor(d, m, 64);
                int   ov = __shfl_xor(v, m, 64);
                if (od < d || (od == d && ov < v)) { d = od; v = ov; }
            }
            if (l15 == 0) {
                int q = qb0 + qh * 64 + ti * 16 + quad * 4 + r;
                if (q < N) {
                    size_t o = (size_t)q * (vslices * 2) + blockIdx.y * 2 + vh;
                    pbD[o] = d;
                    pbI[o] = v;
                }
            }
        }
}

// ---------------- Keys cubic a=-0.5 (matches jax) ----------------
__device__ __forceinline__ float cubic_k(float x) {
    if (x <= 1.f) return (1.5f * x - 2.5f) * x * x + 1.f;
    if (x < 2.f)  return ((-0.5f * x + 2.5f) * x - 4.f) * x + 2.f;
    return 0.f;
}

// ---------------- fused argmin + upsample -> h planes ----------------
// grid = (32 b * 16 cig), 256 threads = pixel; 8 channels per thread.
template <int PN>
__global__ __launch_bounds__(256)
void upsample_pack(const float* __restrict__ emb,
                   const float* __restrict__ pbD, const int* __restrict__ pbI, int vsplit,
                   short* __restrict__ hhi, short* __restrict__ hlo,
                   float* __restrict__ hfp) {
    const int t = threadIdx.x;
    const int x = t & 15, y = t >> 4;
    const int b = blockIdx.x >> 4;
    const int c0 = (blockIdx.x & 15) * 8;

    float val[8];

    if (PN == 16) {
        int q = b * 256 + t;
        float bd = pbD[(size_t)q * vsplit];
        int   bi = pbI[(size_t)q * vsplit];
        for (int j = 1; j < vsplit; j++) {
            float d  = pbD[(size_t)q * vsplit + j];
            int   i2 = pbI[(size_t)q * vsplit + j];
            if (d < bd || (d == bd && i2 < bi)) { bd = d; bi = i2; }
        }
        float4 v0 = *(const float4*)(emb + (size_t)bi * CC + c0);
        float4 v1 = *(const float4*)(emb + (size_t)bi * CC + c0 + 4);
        val[0]=v0.x; val[1]=v0.y; val[2]=v0.z; val[3]=v0.w;
        val[4]=v1.x; val[5]=v1.y; val[6]=v1.z; val[7]=v1.w;
    } else {
        __shared__ int idxL[PN * PN];
        __shared__ float S[PN * PN][8];
        if (t < PN * PN) {
            int q = b * PN * PN + t;
            float bd = pbD[(size_t)q * vsplit];
            int   bi = pbI[(size_t)q * vsplit];
            for (int j = 1; j < vsplit; j++) {
                float d  = pbD[(size_t)q * vsplit + j];
                int   i2 = pbI[(size_t)q * vsplit + j];
                if (d < bd || (d == bd && i2 < bi)) { bd = d; bi = i2; }
            }
            idxL[t] = bi;
        }
        __syncthreads();
        if (t < PN * PN) {
            float4 v0 = *(const float4*)(emb + (size_t)idxL[t] * CC + c0);
            float4 v1 = *(const float4*)(emb + (size_t)idxL[t] * CC + c0 + 4);
            S[t][0]=v0.x; S[t][1]=v0.y; S[t][2]=v0.z; S[t][3]=v0.w;
            S[t][4]=v1.x; S[t][5]=v1.y; S[t][6]=v1.z; S[t][7]=v1.w;
        }
        __syncthreads();

        const float sc = (float)PN / 16.f;
        float sy = (y + 0.5f) * sc - 0.5f;
        float sx = (x + 0.5f) * sc - 0.5f;
        int iy0 = (int)floorf(sy) - 1;
        int ix0 = (int)floorf(sx) - 1;
        float wy[4], wx[4];
        float ssy = 0.f, ssx = 0.f;
#pragma unroll
        for (int k = 0; k < 4; k++) {
            int iy = iy0 + k, ix = ix0 + k;
            float a = (iy >= 0 && iy < PN) ? cubic_k(fabsf(sy - (float)iy)) : 0.f;
            float bb = (ix >= 0 && ix < PN) ? cubic_k(fabsf(sx - (float)ix)) : 0.f;
            wy[k] = a; ssy += a;
            wx[k] = bb; ssx += bb;
        }
        float ry = 1.f / ssy, rx = 1.f / ssx;
#pragma unroll
        for (int k = 0; k < 4; k++) { wy[k] *= ry; wx[k] *= rx; }

#pragma unroll
        for (int j = 0; j < 8; j++) val[j] = 0.f;
#pragma unroll
        for (int k4 = 0; k4 < 4; k4++) {
            int iy = iy0 + k4;
            if (iy < 0 || iy >= PN) continue;
#pragma unroll
            for (int j4 = 0; j4 < 4; j4++) {
                int ix = ix0 + j4;
                if (ix < 0 || ix >= PN) continue;
                float w = wy[k4] * wx[j4];
                const float* sp = S[iy * PN + ix];
#pragma unroll
                for (int j = 0; j < 8; j++) val[j] = fmaf(w, sp[j], val[j]);
            }
        }
    }

    short hs[8], ls[8];
#pragma unroll
    for (int j = 0; j < 8; j++) {
        uint32_t u = pack_hilo(val[j]);
        hs[j] = (short)(u >> 16);
        ls[j] = (short)(u & 0xffffu);
    }
    size_t ho = ((size_t)(b * 18 + y + 1) * 18 + (x + 1)) * CC + c0;
    *(short8*)(hhi + ho) = *(short8*)hs;
    *(short8*)(hlo + ho) = *(short8*)ls;
#pragma unroll
    for (int j = 0; j < 8; j++)
        hfp[((size_t)b * CC + c0 + j) * 256 + t] = val[j];
}

// ---------------- MFMA conv3x3: LDS-shared weights, K-split (R5 structure) ----------------
template <bool FIRST>
__global__ __launch_bounds__(256)
void conv_mfma(const short* __restrict__ Whi, const short* __restrict__ Wlo,
               const short* __restrict__ hhi, const short* __restrict__ hlo,
               const float* __restrict__ hfp, const float* __restrict__ pb,
               const float* __restrict__ f, float* __restrict__ f_hat,
               float* __restrict__ lacc, int kphi) {
    __shared__ short Bsh[64 * CSTR];
    __shared__ short Bsl[64 * CSTR];
    __shared__ float red[2][16][65];
    __shared__ float lred[2];

    const int t = threadIdx.x;
    const int wave = t >> 6, lane = t & 63;
    const int quad = lane >> 4, l15 = lane & 15;
    const int pxg = wave & 1, kh = wave >> 1;
    const int cH = blockIdx.x & 1;
    const int pc = blockIdx.x >> 1;
    const int b = pc >> 3;
    const int pxbase = (pc & 7) * 32;
    const int pa = pxbase + pxg * 16 + l15;
    const int ya = pa >> 4, xa = pa & 15;

    floatx4 acc[4];
    floatx4 z = {0.f, 0.f, 0.f, 0.f};
#pragma unroll
    for (int nt = 0; nt < 4; nt++) acc[nt] = z;

    for (int kk = 0; kk < 9; kk++) {
        __syncthreads();
        {
            const short* gh = Whi + ((size_t)(kphi * 9 + kk) * CC + cH * 64) * CC;
            const short* gl = Wlo + ((size_t)(kphi * 9 + kk) * CC + cH * 64) * CC;
#pragma unroll
            for (int i = 0; i < 4; i++) {
                int chunk = i * 256 + t;
                int row = chunk >> 4, col = (chunk & 15) * 8;
                *(short8*)&Bsh[row * CSTR + col] = *(const short8*)(gh + row * CC + col);
                *(short8*)&Bsl[row * CSTR + col] = *(const short8*)(gl + row * CC + col);
            }
        }
        __syncthreads();

        const int ky = kk / 3, kx = kk % 3;
        const size_t aoff = ((size_t)(b * 18 + ya + ky) * 18 + (xa + kx)) * CC + quad * 8;
#pragma unroll
        for (int i2 = 0; i2 < 2; i2++) {
            const int cic = kh * 2 + i2;
            short8 ah = *(const short8*)(hhi + aoff + cic * 32);
            short8 al = *(const short8*)(hlo + aoff + cic * 32);
#pragma unroll
            for (int nt = 0; nt < 4; nt++) {
                short8 bh = *(const short8*)&Bsh[(nt * 16 + l15) * CSTR + cic * 32 + quad * 8];
                short8 bl = *(const short8*)&Bsl[(nt * 16 + l15) * CSTR + cic * 32 + quad * 8];
                acc[nt] = __builtin_amdgcn_mfma_f32_16x16x32_bf16(ah, bh, acc[nt], 0, 0, 0);
                acc[nt] = __builtin_amdgcn_mfma_f32_16x16x32_bf16(al, bh, acc[nt], 0, 0, 0);
                acc[nt] = __builtin_amdgcn_mfma_f32_16x16x32_bf16(ah, bl, acc[nt], 0, 0, 0);
            }
        }
    }

    __syncthreads();
    if (kh == 1) {
#pragma unroll
        for (int nt = 0; nt < 4; nt++)
#pragma unroll
            for (int r = 0; r < 4; r++)
                red[pxg][quad * 4 + r][nt * 16 + l15] = acc[nt][r];
    }
    __syncthreads();

    if (kh == 0) {
        const int pe = pxbase + pxg * 16 + quad * 4;
        float lsum = 0.f;
#pragma unroll
        for (int nt = 0; nt < 4; nt++) {
            int cout = cH * 64 + nt * 16 + l15;
            float bias = pb[kphi * CC + cout];
            size_t gi = ((size_t)b * CC + cout) * 256 + pe;
            float4 h4  = *(const float4*)(hfp + gi);
            float4 f4  = *(const float4*)(f + gi);
            float4 fh4 = FIRST ? make_float4(0.f, 0.f, 0.f, 0.f) : *(const float4*)(f_hat + gi);
            float c0 = acc[nt][0] + red[pxg][quad * 4 + 0][nt * 16 + l15] + bias;
            float c1 = acc[nt][1] + red[pxg][quad * 4 + 1][nt * 16 + l15] + bias;
            float c2 = acc[nt][2] + red[pxg][quad * 4 + 2][nt * 16 + l15] + bias;
            float c3 = acc[nt][3] + red[pxg][quad * 4 + 3][nt * 16 + l15] + bias;
            float o0 = fh4.x + 0.5f * h4.x + 0.5f * c0;
            float o1 = fh4.y + 0.5f * h4.y + 0.5f * c1;
            float o2 = fh4.z + 0.5f * h4.z + 0.5f * c2;
            float o3 = fh4.w + 0.5f * h4.w + 0.5f * c3;
            *(float4*)(f_hat + gi) = make_float4(o0, o1, o2, o3);
            float d0 = o0 - f4.x, d1 = o1 - f4.y, d2 = o2 - f4.z, d3 = o3 - f4.w;
            lsum += d0*d0 + d1*d1 + d2*d2 + d3*d3;
        }
#pragma unroll
        for (int off = 32; off; off >>= 1) lsum += __shfl_down(lsum, off, 64);
        if (lane == 0) lred[pxg] = lsum;
    }
    __syncthreads();
    if (t == 0) atomicAdd(lacc, lred[0] + lred[1]);
}

__global__ void finalize_kernel(const float* __restrict__ lacc, float* __restrict__ out_loss) {
    *out_loss = lacc[0] * (0.25f / (float)NELEM);   // (1+BETA)/SN * sum of means
}

extern "C" void kernel_launch(void* const* d_in, const int* in_sizes, int n_in,
                              void* d_out, int out_size, void* d_ws, size_t ws_size,
                              hipStream_t stream) {
    const float* f   = (const float*)d_in[0];
    const float* emb = (const float*)d_in[1];
    const float* pw  = (const float*)d_in[2];
    const float* pb  = (const float*)d_in[3];
    float* out = (float*)d_out;

    uint32_t* w32 = (uint32_t*)d_ws;
    short* rphi = (short*)(w32);                    // 1,048,576 shorts
    short* rplo = (short*)(w32 + 524288);
    short* ephi = (short*)(w32 + 1048576);          // 1,048,576 shorts
    short* eplo = (short*)(w32 + 1572864);
    short* Whi  = (short*)(w32 + 2097152);          // 589,824 shorts
    short* Wlo  = (short*)(w32 + 2392064);
    short* hhi  = (short*)(w32 + 2686976);          // 1,327,104 shorts
    short* hlo  = (short*)(w32 + 3350528);
    float* hfp  = (float*)(w32 + 4014080);          // 1,048,576 f
    float* esq  = (float*)(w32 + 5062656);          // 8192
    float* pbD  = (float*)(w32 + 5070848);          // 131072
    int*   pbI  = (int*)  (w32 + 5201920);          // 131072
    float* lacc = (float*)(w32 + 5332992);          // 1

    // zero halos of h planes (hhi & hlo contiguous)
    hipMemsetAsync(hhi, 0, (size_t)2 * 1327104 * sizeof(short), stream);

    esq_pack<<<512, 256, 0, stream>>>(emb, esq, ephi, eplo, lacc);
    prepack_w<<<256, 256, 0, stream>>>(pw, Whi, Wlo);

    // mirror np.linspace(1/12, 11/12, 4) exactly in float64
    double start = 1.0 / 12.0;
    double stop  = 1.0 - 1.0 / 12.0;
    double step  = (stop - start) / 3.0;
    double ticks[4] = {start, 1.0 * step + start, 2.0 * step + start, stop};

    const int pns[5]    = {1, 2, 4, 8, 16};
    const int gridy5[5] = {64, 64, 32, 16, 8};      // vslices
    const int vtPB5[5]  = {1, 1, 2, 4, 8};          // vtiles per block

    for (int si = 0; si < 5; si++) {
        int pn = pns[si];
        int N  = BB * pn * pn;
        double tt = (double)si / 4.0;
        int kphi = 0;
        double bd = fabs(ticks[0] - tt);
        for (int i = 1; i < 4; i++) {
            double d = fabs(ticks[i] - tt);
            if (d < bd) { bd = d; kphi = i; }   // np.argmin: first occurrence
        }

        if (si == 0) pool_pack<true><<<(N * CC) / 256, 256, 0, stream>>>(f, out, rphi, rplo, pn);
        else         pool_pack<false><<<(N * CC) / 256, 256, 0, stream>>>(f, out, rphi, rplo, pn);

        int qb = (N + 127) / 128;
        dim3 dgrid(qb, gridy5[si]);
        dist_mfma<<<dgrid, 256, 0, stream>>>(rphi, rplo, ephi, eplo, esq, pbD, pbI, N, vtPB5[si]);

        int vsplit = gridy5[si] * 2;
        switch (pn) {
            case 1:  upsample_pack<1><<<512, 256, 0, stream>>>(emb, pbD, pbI, vsplit, hhi, hlo, hfp); break;
            case 2:  upsample_pack<2><<<512, 256, 0, stream>>>(emb, pbD, pbI, vsplit, hhi, hlo, hfp); break;
            case 4:  upsample_pack<4><<<512, 256, 0, stream>>>(emb, pbD, pbI, vsplit, hhi, hlo, hfp); break;
            case 8:  upsample_pack<8><<<512, 256, 0, stream>>>(emb, pbD, pbI, vsplit, hhi, hlo, hfp); break;
            default: upsample_pack<16><<<512, 256, 0, stream>>>(emb, pbD, pbI, vsplit, hhi, hlo, hfp); break;
        }

        if (si == 0) conv_mfma<true><<<512, 256, 0, stream>>>(Whi, Wlo, hhi, hlo, hfp, pb, f, out, lacc, kphi);
        else         conv_mfma<false><<<512, 256, 0, stream>>>(Whi, Wlo, hhi, hlo, hfp, pb, f, out, lacc, kphi);
    }

    finalize_kernel<<<1, 1, 0, stream>>>(lacc, out + NELEM);
}